// Round 7
// baseline (266.299 us; speedup 1.0000x reference)
//
#include <hip/hip_runtime.h>
#include <stdint.h>

#define NB 4
#define CC 256
#define C16 16
#define HH 64
#define WW 64
#define NN 4096

typedef __attribute__((ext_vector_type(8))) short short8;
typedef __attribute__((ext_vector_type(4))) float floatx4;
typedef __attribute__((ext_vector_type(16))) float floatx16;

__device__ __forceinline__ unsigned short f2bf(float f) {
    union { float f; unsigned u; } v; v.f = f;
    unsigned r = v.u + 0x7fffu + ((v.u >> 16) & 1u);
    return (unsigned short)(r >> 16);
}

// ========== K1: cast x->xT bf16 [b][n][c], cast wv/wq/wk -> bf16, zero nu2 ==========
__global__ __launch_bounds__(256) void prep_kernel(
        const float* __restrict__ x, const float* __restrict__ wv,
        const float* __restrict__ wq, const float* __restrict__ wk,
        unsigned short* __restrict__ xT, unsigned short* __restrict__ wvb,
        unsigned short* __restrict__ wqkb, float* __restrict__ nu2) {
    int bid = blockIdx.x;
    if (bid < 1024) {
        __shared__ float tile[64][65];
        int nt = bid & 63, ct = (bid >> 6) & 3, b = bid >> 8;
        int n0 = nt * 64, c0 = ct * 64;
        int ln = threadIdx.x & 63, grp = threadIdx.x >> 6;
        const float* xb = x + ((size_t)b * CC + c0) * NN + n0;
        for (int i = 0; i < 16; ++i) {
            int c = i * 4 + grp;
            tile[c][ln] = xb[(size_t)c * NN + ln];
        }
        __syncthreads();
        unsigned short* xtb = xT + ((size_t)b * NN + n0) * CC + c0;
        for (int i = 0; i < 16; ++i) {
            int n = i * 4 + grp;
            xtb[(size_t)n * CC + ln] = f2bf(tile[ln][n]);
        }
    } else {
        int idx = (bid - 1024) * 256 + threadIdx.x;
        if (bid == 1024 && threadIdx.x < 128) nu2[threadIdx.x] = 0.f;
        if (idx < 16384) {
            float4 v = *(const float4*)(wv + idx * 4);
            ushort4 o;
            o.x = f2bf(v.x); o.y = f2bf(v.y); o.z = f2bf(v.z); o.w = f2bf(v.w);
            *(ushort4*)(wvb + idx * 4) = o;
        } else if (idx < 16384 + 6144) {
            int base = (idx - 16384) * 4;
#pragma unroll
            for (int u = 0; u < 4; ++u) {
                int e = base + u;
                int t = e / 12288;
                int i = e - t * 12288;
                int tap = i >> 12, o = (i >> 8) & 15, c = i & 255;
                const float* src = t ? wk : wq;
                wqkb[e] = f2bf(src[o * 768 + c * 3 + tap]);
            }
        }
    }
}

// ========== K2: conv_v (blocks 0..511) + conv_qk w/ fused FRN-ssq atomics (512..767) ==========
__global__ __launch_bounds__(256) void conv_kernel(
        const unsigned short* __restrict__ xT, const unsigned short* __restrict__ wvb,
        const unsigned short* __restrict__ wqkb, const float* __restrict__ bv,
        const float* __restrict__ bq, const float* __restrict__ bk,
        unsigned short* __restrict__ vb, float* __restrict__ qraw,
        float* __restrict__ kraw, float* __restrict__ nu2) {
    int bid = blockIdx.x;
    int tid = threadIdx.x;
    int wv_ = tid >> 6, lane = tid & 63;
    int q16 = lane >> 4, c16 = lane & 15;
    if (bid < 512) {
        // ---- conv_v: 1x1 conv via MFMA, 64n x 128c per block ----
        int ntile = bid & 63, b = (bid >> 6) & 3, ch = bid >> 8;   // ch 0..1
        int n0 = ntile * 64;
        int cb = ch * 128 + wv_ * 32;
        floatx4 fzero = {0.f, 0.f, 0.f, 0.f};
        floatx4 acc[2][4];
        for (int ct = 0; ct < 2; ++ct)
            for (int nt = 0; nt < 4; ++nt) acc[ct][nt] = fzero;
        const unsigned short* xb = xT + ((size_t)b * NN + n0) * CC;
        for (int kc = 0; kc < 8; ++kc) {
            int ko = kc * 32 + q16 * 8;
            short8 a0 = *(const short8*)(wvb + (size_t)(cb + c16) * CC + ko);
            short8 a1 = *(const short8*)(wvb + (size_t)(cb + 16 + c16) * CC + ko);
            short8 bf[4];
#pragma unroll
            for (int nt = 0; nt < 4; ++nt)
                bf[nt] = *(const short8*)(xb + (size_t)(nt * 16 + c16) * CC + ko);
#pragma unroll
            for (int nt = 0; nt < 4; ++nt) {
                acc[0][nt] = __builtin_amdgcn_mfma_f32_16x16x32_bf16(a0, bf[nt], acc[0][nt], 0, 0, 0);
                acc[1][nt] = __builtin_amdgcn_mfma_f32_16x16x32_bf16(a1, bf[nt], acc[1][nt], 0, 0, 0);
            }
        }
#pragma unroll
        for (int ct = 0; ct < 2; ++ct)
            for (int nt = 0; nt < 4; ++nt)
                for (int r = 0; r < 4; ++r) {
                    int c = cb + ct * 16 + q16 * 4 + r;
                    vb[(size_t)(b * CC + c) * NN + n0 + nt * 16 + c16] = f2bf(acc[ct][nt][r] + bv[c]);
                }
    } else {
        // ---- conv_qk via MFMA im2col + fused sum-of-squares atomics ----
        int cv = bid - 512;
        int nb = cv & 63, b = cv >> 6;
        int n = nb * 64 + wv_ * 16 + c16;
        int h = n >> 6, w = n & 63;
        bool vm1 = (w != 0), vp1 = (w != 63);
        bool vm64 = (h != 0), vp64 = (h != 63);
        short8 zero8 = {0, 0, 0, 0, 0, 0, 0, 0};
        floatx4 accq = {0.f, 0.f, 0.f, 0.f}, acck = {0.f, 0.f, 0.f, 0.f};
        const unsigned short* xb = xT + (size_t)b * NN * CC;
        const unsigned short* wrow = wqkb + c16 * 256;
        for (int kc = 0; kc < 8; ++kc) {
            int ko = kc * 32 + q16 * 8;
            short8 b0 = *(const short8*)(xb + (size_t)n * CC + ko);
            short8 bm1 = vm1 ? *(const short8*)(xb + (size_t)(n - 1) * CC + ko) : zero8;
            short8 bp1 = vp1 ? *(const short8*)(xb + (size_t)(n + 1) * CC + ko) : zero8;
            short8 bm64 = vm64 ? *(const short8*)(xb + (size_t)(n - 64) * CC + ko) : zero8;
            short8 bp64 = vp64 ? *(const short8*)(xb + (size_t)(n + 64) * CC + ko) : zero8;
            short8 aq0 = *(const short8*)(wrow + 0 * 4096 + ko);
            short8 aq1 = *(const short8*)(wrow + 1 * 4096 + ko);
            short8 aq2 = *(const short8*)(wrow + 2 * 4096 + ko);
            short8 ak0 = *(const short8*)(wrow + 12288 + 0 * 4096 + ko);
            short8 ak1 = *(const short8*)(wrow + 12288 + 1 * 4096 + ko);
            short8 ak2 = *(const short8*)(wrow + 12288 + 2 * 4096 + ko);
            accq = __builtin_amdgcn_mfma_f32_16x16x32_bf16(aq0, bm1, accq, 0, 0, 0);
            accq = __builtin_amdgcn_mfma_f32_16x16x32_bf16(aq1, b0, accq, 0, 0, 0);
            accq = __builtin_amdgcn_mfma_f32_16x16x32_bf16(aq2, bp1, accq, 0, 0, 0);
            acck = __builtin_amdgcn_mfma_f32_16x16x32_bf16(ak0, bm64, acck, 0, 0, 0);
            acck = __builtin_amdgcn_mfma_f32_16x16x32_bf16(ak1, b0, acck, 0, 0, 0);
            acck = __builtin_amdgcn_mfma_f32_16x16x32_bf16(ak2, bp64, acck, 0, 0, 0);
        }
        float sq[4], sk[4];
#pragma unroll
        for (int r = 0; r < 4; ++r) {
            int o = q16 * 4 + r;
            float vq = accq[r] + bq[o];
            float vk = acck[r] + bk[o];
            qraw[(size_t)(b * C16 + o) * NN + n] = vq;
            kraw[(size_t)(b * C16 + o) * NN + n] = vk;
            sq[r] = vq * vq; sk[r] = vk * vk;
        }
        // reduce ssq over the 16 c16-lanes, one atomic per (o, tensor)
#pragma unroll
        for (int r = 0; r < 4; ++r) {
#pragma unroll
            for (int off = 1; off < 16; off <<= 1) {
                sq[r] += __shfl_xor(sq[r], off, 64);
                sk[r] += __shfl_xor(sk[r], off, 64);
            }
        }
        if (c16 == 0) {
#pragma unroll
            for (int r = 0; r < 4; ++r) {
                int o = q16 * 4 + r;
                atomicAdd(nu2 + b * C16 + o, sq[r]);
                atomicAdd(nu2 + 64 + b * C16 + o, sk[r]);
            }
        }
    }
}

// ========== K3: FRN normalize + Mish, transpose-write bf16 [b][n][16] ==========
// q additionally scaled by log2(e) so attention can use exp2.
__global__ __launch_bounds__(256) void frn_mish_kernel(
        const float* __restrict__ qraw, const float* __restrict__ kraw,
        const float* __restrict__ nu2, const float* __restrict__ eps_q,
        const float* __restrict__ eps_k, unsigned short* __restrict__ qb,
        unsigned short* __restrict__ kb) {
    int blk = blockIdx.x;
    int tensor = blk >> 6;
    int b = (blk >> 4) & 3;
    int ch = blk & 15;
    const float* raw = tensor ? kraw : qraw;
    const float* eps = tensor ? eps_k : eps_q;
    unsigned short* outp = tensor ? kb : qb;
    const float* nu = nu2 + tensor * 64 + b * C16;
    float scale = tensor ? 1.0f : 1.44269504f;
    int n = ch * 256 + threadIdx.x;
    union { unsigned short s[16]; uint4 u[2]; } pk;
    for (int o = 0; o < C16; ++o) {
        float r = raw[(size_t)(b * C16 + o) * NN + n];
        float v = r * rsqrtf(nu[o] * (1.f / (float)NN) + fabsf(eps[o]));
        float sp = fmaxf(v, 0.f) + log1pf(expf(-fabsf(v)));   // stable softplus
        pk.s[o] = f2bf(v * tanhf(sp) * scale);
    }
    uint4* dst = (uint4*)(outp + (size_t)(b * NN + n) * C16);
    dst[0] = pk.u[0];
    dst[1] = pk.u[1];
}

// exp2 + pack to bf16 A-frags (half-lane exchange); lsum accumulated
__device__ __forceinline__ void pack_p(
        floatx16 sc, float mneg, bool hi, short8* A0, short8* A1, float* lsum) {
    unsigned pk[8];
    float ls = 0.f;
#pragma unroll
    for (int p = 0; p < 8; ++p) {
        float e0 = exp2f(sc[2 * p] + mneg);
        float e1 = exp2f(sc[2 * p + 1] + mneg);
        ls += e0 + e1;
        pk[p] = __builtin_amdgcn_perm(__float_as_uint(e1), __float_as_uint(e0), 0x07060302u);
    }
    *lsum += ls;
    unsigned xk[8];
#pragma unroll
    for (int p = 0; p < 8; ++p) xk[p] = (unsigned)__shfl_xor((int)pk[p], 32, 64);
    union { unsigned u[4]; short8 s; } a0, a1;
    a0.u[0] = hi ? xk[2] : pk[0]; a0.u[1] = hi ? xk[3] : pk[1];
    a0.u[2] = hi ? pk[2] : xk[0]; a0.u[3] = hi ? pk[3] : xk[1];
    a1.u[0] = hi ? xk[6] : pk[4]; a1.u[1] = hi ? xk[7] : pk[5];
    a1.u[2] = hi ? pk[6] : xk[4]; a1.u[3] = hi ? pk[7] : xk[5];
    *A0 = a0.s; *A1 = a1.s;
}

// ========== K4: attention, barrier-free main loop, j=64 c=64 per block ==========
// grid 1024: cs = id&3 (64-c slice), b = (id>>2)&3, jt = id>>4 (64-j tile).
// 4 blocks/CU. Wave w streams k in [1024w, 1024w+1024) in 32-k steps.
__global__ __launch_bounds__(256, 4) void attn_kernel(
        const unsigned short* __restrict__ qb, const unsigned short* __restrict__ kb,
        const unsigned short* __restrict__ vb, const float* __restrict__ x,
        const float* __restrict__ gamma_p, float* __restrict__ out) {
    __shared__ float mp[4][2][32];
    __shared__ float lpart[4][2][32];
    __shared__ float obuf[4][32][33];

    int tid = threadIdx.x;
    int wv_ = __builtin_amdgcn_readfirstlane(tid >> 6);
    int lane = tid & 63;
    int l31 = lane & 31, lh = lane >> 5;
    bool hi = (lh != 0);
    int id = blockIdx.x;
    int cs = id & 3, b = (id >> 2) & 3, jt = id >> 4;
    int jbase = jt * 64, cb = cs * 64;

    const unsigned short* qbb = qb + (size_t)b * NN * C16;
    const unsigned short* kbb = kb + (size_t)b * NN * C16;
    const unsigned short* vbb = vb + ((size_t)b * CC + cb) * NN;

    short8 qf0 = *(const short8*)(qbb + (size_t)(jbase + l31) * C16 + lh * 8);
    short8 qf1 = *(const short8*)(qbb + (size_t)(jbase + 32 + l31) * C16 + lh * 8);

    floatx16 z16 = {0,0,0,0,0,0,0,0,0,0,0,0,0,0,0,0};
    int kw = wv_ * 1024;

    // ---- pre-pass: row max over this wave's k-range ----
    float mx0 = -INFINITY, mx1 = -INFINITY;
    {
        short8 a0 = *(const short8*)(kbb + (size_t)(kw + l31) * C16 + lh * 8);
        short8 a1 = *(const short8*)(kbb + (size_t)(kw + 32 + l31) * C16 + lh * 8);
#pragma unroll 1
        for (int s = 0; s < 32; s += 2) {
            floatx16 s0 = __builtin_amdgcn_mfma_f32_32x32x16_bf16(a0, qf0, z16, 0, 0, 0);
            floatx16 s1 = __builtin_amdgcn_mfma_f32_32x32x16_bf16(a0, qf1, z16, 0, 0, 0);
            a0 = *(const short8*)(kbb + (size_t)(kw + ((s + 2) & 31) * 32 + l31) * C16 + lh * 8);
            floatx16 s2 = __builtin_amdgcn_mfma_f32_32x32x16_bf16(a1, qf0, z16, 0, 0, 0);
            floatx16 s3 = __builtin_amdgcn_mfma_f32_32x32x16_bf16(a1, qf1, z16, 0, 0, 0);
            a1 = *(const short8*)(kbb + (size_t)(kw + ((s + 3) & 31) * 32 + l31) * C16 + lh * 8);
#pragma unroll
            for (int r = 0; r < 16; ++r) {
                mx0 = fmaxf(mx0, fmaxf(s0[r], s2[r]));
                mx1 = fmaxf(mx1, fmaxf(s1[r], s3[r]));
            }
        }
    }
    mx0 = fmaxf(mx0, __shfl_xor(mx0, 32, 64));
    mx1 = fmaxf(mx1, __shfl_xor(mx1, 32, 64));
    if (lh == 0) { mp[wv_][0][l31] = mx0; mp[wv_][1][l31] = mx1; }
    __syncthreads();
    float mneg0 = -fmaxf(fmaxf(mp[0][0][l31], mp[1][0][l31]),
                         fmaxf(mp[2][0][l31], mp[3][0][l31]));
    float mneg1 = -fmaxf(fmaxf(mp[0][1][l31], mp[1][1][l31]),
                         fmaxf(mp[2][1][l31], mp[3][1][l31]));

    // ---- main loop ----
    floatx16 acc0[2], acc1[2];
    acc0[0] = z16; acc0[1] = z16; acc1[0] = z16; acc1[1] = z16;
    float lsum0 = 0.f, lsum1 = 0.f;

    short8 ak = *(const short8*)(kbb + (size_t)(kw + l31) * C16 + lh * 8);
#pragma unroll 1
    for (int step = 0; step < 32; ++step) {
        int kg = kw + step * 32;
        floatx16 sc0 = __builtin_amdgcn_mfma_f32_32x32x16_bf16(ak, qf0, z16, 0, 0, 0);
        floatx16 sc1 = __builtin_amdgcn_mfma_f32_32x32x16_bf16(ak, qf1, z16, 0, 0, 0);
        ak = *(const short8*)(kbb + (size_t)(kw + ((step + 1) & 31) * 32 + l31) * C16 + lh * 8);
        short8 A00, A01, A10, A11;
        pack_p(sc0, mneg0, hi, &A00, &A01, &lsum0);
        pack_p(sc1, mneg1, hi, &A10, &A11, &lsum1);
        // PV: V-frags shared across both j-groups
#pragma unroll
        for (int cg = 0; cg < 2; ++cg) {
            short8 vfa = *(const short8*)(vbb + (size_t)(cg * 32 + l31) * NN + kg + lh * 8);
            short8 vfb = *(const short8*)(vbb + (size_t)(cg * 32 + l31) * NN + kg + 16 + lh * 8);
            acc0[cg] = __builtin_amdgcn_mfma_f32_32x32x16_bf16(A00, vfa, acc0[cg], 0, 0, 0);
            acc0[cg] = __builtin_amdgcn_mfma_f32_32x32x16_bf16(A01, vfb, acc0[cg], 0, 0, 0);
            acc1[cg] = __builtin_amdgcn_mfma_f32_32x32x16_bf16(A10, vfa, acc1[cg], 0, 0, 0);
            acc1[cg] = __builtin_amdgcn_mfma_f32_32x32x16_bf16(A11, vfb, acc1[cg], 0, 0, 0);
        }
    }

    // l partials
    lsum0 += __shfl_xor(lsum0, 32, 64);
    lsum1 += __shfl_xor(lsum1, 32, 64);
    if (lh == 0) { lpart[wv_][0][l31] = lsum0; lpart[wv_][1][l31] = lsum1; }
    __syncthreads();

    int j31 = tid & 31;
    float gamma = gamma_p[0];
    float gl0 = gamma / (lpart[0][0][j31] + lpart[1][0][j31] + lpart[2][0][j31] + lpart[3][0][j31]);
    float gl1 = gamma / (lpart[0][1][j31] + lpart[1][1][j31] + lpart[2][1][j31] + lpart[3][1][j31]);
    const float* xbb = x + (size_t)b * CC * NN;
    float* obb = out + (size_t)b * CC * NN;
    int hofs = lh * 4;
    int cgrp = tid >> 5;   // 0..7 -> 4 c-rows each
    // O reduction over waves, one (jg, cg) 32x32 tile at a time
    // write: obuf[w][j(mfma row)][c(l31)]; read MUST be obuf[w][j31][c]
#pragma unroll
    for (int jg = 0; jg < 2; ++jg) {
        float gl = jg ? gl1 : gl0;
#pragma unroll
        for (int cg = 0; cg < 2; ++cg) {
            __syncthreads();
            const floatx16& a = jg ? acc1[cg] : acc0[cg];
#pragma unroll
            for (int r = 0; r < 16; ++r) {
                int row = (r & 3) + 8 * (r >> 2) + hofs;
                obuf[wv_][row][l31] = a[r];
            }
            __syncthreads();
#pragma unroll
            for (int i = 0; i < 4; ++i) {
                int c = cgrp * 4 + i;
                float val = obuf[0][j31][c] + obuf[1][j31][c] + obuf[2][j31][c] + obuf[3][j31][c];
                size_t oidx = (size_t)(cb + cg * 32 + c) * NN + jbase + jg * 32 + j31;
                obb[oidx] = fmaf(gl, val, xbb[oidx]);
            }
        }
    }
}

extern "C" void kernel_launch(void* const* d_in, const int* in_sizes, int n_in,
                              void* d_out, int out_size, void* d_ws, size_t ws_size,
                              hipStream_t stream) {
    const float* x     = (const float*)d_in[0];
    const float* wq    = (const float*)d_in[1];
    const float* bq    = (const float*)d_in[2];
    const float* wk    = (const float*)d_in[3];
    const float* bk    = (const float*)d_in[4];
    const float* wv    = (const float*)d_in[5];
    const float* bv    = (const float*)d_in[6];
    const float* gamma = (const float*)d_in[7];
    const float* eps_q = (const float*)d_in[8];
    const float* eps_k = (const float*)d_in[9];
    float* out = (float*)d_out;

    char* ws = (char*)d_ws;
    float* qraw = (float*)ws;                                        // 1 MB
    float* kraw = (float*)(ws + (1u << 20));                         // 1 MB
    float* nu2  = (float*)(ws + (2u << 20));                         // 512 B
    unsigned short* qb = (unsigned short*)(ws + (2u << 20) + 4096);  // 512 KB
    unsigned short* kb = qb + (size_t)NB * NN * C16;                 // 512 KB
    unsigned short* vb = kb + (size_t)NB * NN * C16;                 // 8 MB
    unsigned short* xT = vb + (size_t)NB * CC * NN;                  // 8 MB
    unsigned short* wvb = xT + (size_t)NB * NN * CC;                 // 128 KB
    unsigned short* wqkb = wvb + (size_t)CC * CC;                    // 48 KB

    prep_kernel<<<dim3(1112), dim3(256), 0, stream>>>(x, wv, wq, wk, xT, wvb, wqkb, nu2);
    conv_kernel<<<dim3(768), dim3(256), 0, stream>>>(xT, wvb, wqkb, bv, bq, bk, vb, qraw, kraw, nu2);
    frn_mish_kernel<<<dim3(128), dim3(256), 0, stream>>>(qraw, kraw, nu2, eps_q, eps_k, qb, kb);
    attn_kernel<<<dim3(1024), dim3(256), 0, stream>>>(qb, kb, vb, x, gamma, out);
}

// Round 9
// 221.929 us; speedup vs baseline: 1.1999x; 1.1999x over previous
//
#include <hip/hip_runtime.h>
#include <stdint.h>

#define NB 4
#define CC 256
#define C16 16
#define HH 64
#define WW 64
#define NN 4096

typedef __attribute__((ext_vector_type(8))) short short8;
typedef __attribute__((ext_vector_type(4))) float floatx4;
typedef __attribute__((ext_vector_type(16))) float floatx16;

#if __has_builtin(__builtin_amdgcn_exp2f)
#define EXP2(x) __builtin_amdgcn_exp2f(x)
#else
#define EXP2(x) exp2f(x)
#endif

__device__ __forceinline__ unsigned short f2bf(float f) {
    union { float f; unsigned u; } v; v.f = f;
    unsigned r = v.u + 0x7fffu + ((v.u >> 16) & 1u);
    return (unsigned short)(r >> 16);
}

// ========== K1: cast x->xT bf16 [b][n][c]; cast wv/wq/wk; zero nu2 ==========
__global__ __launch_bounds__(256) void prep_kernel(
        const float* __restrict__ x, const float* __restrict__ wv,
        const float* __restrict__ wq, const float* __restrict__ wk,
        unsigned short* __restrict__ xT, unsigned short* __restrict__ wvb,
        unsigned short* __restrict__ wqkb, float* __restrict__ nu2) {
    int bid = blockIdx.x;
    if (bid < 1024) {
        __shared__ float tile[64][65];
        int nt = bid & 63, ct = (bid >> 6) & 3, b = bid >> 8;
        int n0 = nt * 64, c0 = ct * 64;
        int ln = threadIdx.x & 63, grp = threadIdx.x >> 6;
        const float* xb = x + ((size_t)b * CC + c0) * NN + n0;
        for (int i = 0; i < 16; ++i) {
            int c = i * 4 + grp;
            tile[c][ln] = xb[(size_t)c * NN + ln];
        }
        __syncthreads();
        unsigned short* xtb = xT + ((size_t)b * NN + n0) * CC + c0;
        for (int i = 0; i < 16; ++i) {
            int n = i * 4 + grp;
            xtb[(size_t)n * CC + ln] = f2bf(tile[ln][n]);
        }
    } else {
        int idx = (bid - 1024) * 256 + threadIdx.x;
        if (bid == 1024 && threadIdx.x < 128) nu2[threadIdx.x] = 0.f;
        if (idx < 16384) {
            float4 v = *(const float4*)(wv + idx * 4);
            ushort4 o;
            o.x = f2bf(v.x); o.y = f2bf(v.y); o.z = f2bf(v.z); o.w = f2bf(v.w);
            *(ushort4*)(wvb + idx * 4) = o;
        } else if (idx < 16384 + 6144) {
            int base = (idx - 16384) * 4;
#pragma unroll
            for (int u = 0; u < 4; ++u) {
                int e = base + u;
                int t = e / 12288;
                int i = e - t * 12288;
                int tap = i >> 12, o = (i >> 8) & 15, c = i & 255;
                const float* src = t ? wk : wq;
                wqkb[e] = f2bf(src[o * 768 + c * 3 + tap]);
            }
        }
    }
}

// ========== K2: conv_v (blocks 0..511) + conv_qk w/ fused FRN-ssq atomics ==========
__global__ __launch_bounds__(256) void conv_kernel(
        const unsigned short* __restrict__ xT, const unsigned short* __restrict__ wvb,
        const unsigned short* __restrict__ wqkb, const float* __restrict__ bv,
        const float* __restrict__ bq, const float* __restrict__ bk,
        unsigned short* __restrict__ vb, float* __restrict__ qraw,
        float* __restrict__ kraw, float* __restrict__ nu2) {
    int bid = blockIdx.x;
    int tid = threadIdx.x;
    int wv_ = tid >> 6, lane = tid & 63;
    int q16 = lane >> 4, c16 = lane & 15;
    if (bid < 512) {
        int ntile = bid & 63, b = (bid >> 6) & 3, ch = bid >> 8;
        int n0 = ntile * 64;
        int cb = ch * 128 + wv_ * 32;
        floatx4 fzero = {0.f, 0.f, 0.f, 0.f};
        floatx4 acc[2][4];
        for (int ct = 0; ct < 2; ++ct)
            for (int nt = 0; nt < 4; ++nt) acc[ct][nt] = fzero;
        const unsigned short* xb = xT + ((size_t)b * NN + n0) * CC;
        for (int kc = 0; kc < 8; ++kc) {
            int ko = kc * 32 + q16 * 8;
            short8 a0 = *(const short8*)(wvb + (size_t)(cb + c16) * CC + ko);
            short8 a1 = *(const short8*)(wvb + (size_t)(cb + 16 + c16) * CC + ko);
            short8 bf[4];
#pragma unroll
            for (int nt = 0; nt < 4; ++nt)
                bf[nt] = *(const short8*)(xb + (size_t)(nt * 16 + c16) * CC + ko);
#pragma unroll
            for (int nt = 0; nt < 4; ++nt) {
                acc[0][nt] = __builtin_amdgcn_mfma_f32_16x16x32_bf16(a0, bf[nt], acc[0][nt], 0, 0, 0);
                acc[1][nt] = __builtin_amdgcn_mfma_f32_16x16x32_bf16(a1, bf[nt], acc[1][nt], 0, 0, 0);
            }
        }
#pragma unroll
        for (int ct = 0; ct < 2; ++ct)
            for (int nt = 0; nt < 4; ++nt)
                for (int r = 0; r < 4; ++r) {
                    int c = cb + ct * 16 + q16 * 4 + r;
                    vb[(size_t)(b * CC + c) * NN + n0 + nt * 16 + c16] = f2bf(acc[ct][nt][r] + bv[c]);
                }
    } else {
        int cv = bid - 512;
        int nb = cv & 63, b = cv >> 6;
        int n = nb * 64 + wv_ * 16 + c16;
        int h = n >> 6, w = n & 63;
        bool vm1 = (w != 0), vp1 = (w != 63);
        bool vm64 = (h != 0), vp64 = (h != 63);
        short8 zero8 = {0, 0, 0, 0, 0, 0, 0, 0};
        floatx4 accq = {0.f, 0.f, 0.f, 0.f}, acck = {0.f, 0.f, 0.f, 0.f};
        const unsigned short* xb = xT + (size_t)b * NN * CC;
        const unsigned short* wrow = wqkb + c16 * 256;
        for (int kc = 0; kc < 8; ++kc) {
            int ko = kc * 32 + q16 * 8;
            short8 b0 = *(const short8*)(xb + (size_t)n * CC + ko);
            short8 bm1 = vm1 ? *(const short8*)(xb + (size_t)(n - 1) * CC + ko) : zero8;
            short8 bp1 = vp1 ? *(const short8*)(xb + (size_t)(n + 1) * CC + ko) : zero8;
            short8 bm64 = vm64 ? *(const short8*)(xb + (size_t)(n - 64) * CC + ko) : zero8;
            short8 bp64 = vp64 ? *(const short8*)(xb + (size_t)(n + 64) * CC + ko) : zero8;
            short8 aq0 = *(const short8*)(wrow + 0 * 4096 + ko);
            short8 aq1 = *(const short8*)(wrow + 1 * 4096 + ko);
            short8 aq2 = *(const short8*)(wrow + 2 * 4096 + ko);
            short8 ak0 = *(const short8*)(wrow + 12288 + 0 * 4096 + ko);
            short8 ak1 = *(const short8*)(wrow + 12288 + 1 * 4096 + ko);
            short8 ak2 = *(const short8*)(wrow + 12288 + 2 * 4096 + ko);
            accq = __builtin_amdgcn_mfma_f32_16x16x32_bf16(aq0, bm1, accq, 0, 0, 0);
            accq = __builtin_amdgcn_mfma_f32_16x16x32_bf16(aq1, b0, accq, 0, 0, 0);
            accq = __builtin_amdgcn_mfma_f32_16x16x32_bf16(aq2, bp1, accq, 0, 0, 0);
            acck = __builtin_amdgcn_mfma_f32_16x16x32_bf16(ak0, bm64, acck, 0, 0, 0);
            acck = __builtin_amdgcn_mfma_f32_16x16x32_bf16(ak1, b0, acck, 0, 0, 0);
            acck = __builtin_amdgcn_mfma_f32_16x16x32_bf16(ak2, bp64, acck, 0, 0, 0);
        }
        float sq[4], sk[4];
#pragma unroll
        for (int r = 0; r < 4; ++r) {
            int o = q16 * 4 + r;
            float vq = accq[r] + bq[o];
            float vk = acck[r] + bk[o];
            qraw[(size_t)(b * C16 + o) * NN + n] = vq;
            kraw[(size_t)(b * C16 + o) * NN + n] = vk;
            sq[r] = vq * vq; sk[r] = vk * vk;
        }
#pragma unroll
        for (int r = 0; r < 4; ++r) {
#pragma unroll
            for (int off = 1; off < 16; off <<= 1) {
                sq[r] += __shfl_xor(sq[r], off, 64);
                sk[r] += __shfl_xor(sk[r], off, 64);
            }
        }
        if (c16 == 0) {
#pragma unroll
            for (int r = 0; r < 4; ++r) {
                int o = q16 * 4 + r;
                atomicAdd(nu2 + b * C16 + o, sq[r]);
                atomicAdd(nu2 + 64 + b * C16 + o, sk[r]);
            }
        }
    }
}

// ========== K3: FRN + Mish, transpose-write bf16 [b][n][16] ==========
// q additionally scaled by log2(e) so attention can use exp2.
__global__ __launch_bounds__(256) void frn_mish_kernel(
        const float* __restrict__ qraw, const float* __restrict__ kraw,
        const float* __restrict__ nu2, const float* __restrict__ eps_q,
        const float* __restrict__ eps_k, unsigned short* __restrict__ qb,
        unsigned short* __restrict__ kb) {
    int blk = blockIdx.x;
    int tensor = blk >> 6;
    int b = (blk >> 4) & 3;
    int ch = blk & 15;
    const float* raw = tensor ? kraw : qraw;
    const float* eps = tensor ? eps_k : eps_q;
    unsigned short* outp = tensor ? kb : qb;
    const float* nu = nu2 + tensor * 64 + b * C16;
    float scale = tensor ? 1.0f : 1.44269504f;
    int n = ch * 256 + threadIdx.x;
    union { unsigned short s[16]; uint4 u[2]; } pk;
    for (int o = 0; o < C16; ++o) {
        float r = raw[(size_t)(b * C16 + o) * NN + n];
        float v = r * rsqrtf(nu[o] * (1.f / (float)NN) + fabsf(eps[o]));
        float sp = fmaxf(v, 0.f) + log1pf(expf(-fabsf(v)));   // stable softplus
        pk.s[o] = f2bf(v * tanhf(sp) * scale);
    }
    uint4* dst = (uint4*)(outp + (size_t)(b * NN + n) * C16);
    dst[0] = pk.u[0];
    dst[1] = pk.u[1];
}

// exp2 + pack to bf16 A-frags (half-lane exchange); lsum accumulated
__device__ __forceinline__ void pack_p(
        floatx16 sc, float mneg, bool hi, short8* A0, short8* A1, float* lsum) {
    unsigned pk[8];
    float ls = 0.f;
#pragma unroll
    for (int p = 0; p < 8; ++p) {
        float e0 = EXP2(sc[2 * p] + mneg);
        float e1 = EXP2(sc[2 * p + 1] + mneg);
        ls += e0 + e1;
        pk[p] = __builtin_amdgcn_perm(__float_as_uint(e1), __float_as_uint(e0), 0x07060302u);
    }
    *lsum += ls;
    unsigned xk[8];
#pragma unroll
    for (int p = 0; p < 8; ++p) xk[p] = (unsigned)__shfl_xor((int)pk[p], 32, 64);
    union { unsigned u[4]; short8 s; } a0, a1;
    a0.u[0] = hi ? xk[2] : pk[0]; a0.u[1] = hi ? xk[3] : pk[1];
    a0.u[2] = hi ? pk[2] : xk[0]; a0.u[3] = hi ? pk[3] : xk[1];
    a1.u[0] = hi ? xk[6] : pk[4]; a1.u[1] = hi ? xk[7] : pk[5];
    a1.u[2] = hi ? pk[6] : xk[4]; a1.u[3] = hi ? pk[7] : xk[5];
    *A0 = a0.s; *A1 = a1.s;
}

// ========== K4: attention, j=64 c=128 per block, in-kernel MFMA max pre-pass ==========
// grid 512: cs = id&1 (128-c), b = (id>>1)&3, jt = id>>3. 2 blocks/CU.
// Wave w streams k in [1024w, 1024w+1024) in 32-k steps.
__global__ __launch_bounds__(256, 2) void attn_kernel(
        const unsigned short* __restrict__ qb, const unsigned short* __restrict__ kb,
        const unsigned short* __restrict__ vb, const float* __restrict__ x,
        const float* __restrict__ gamma_p, float* __restrict__ out) {
    __shared__ float mp[4][2][32];
    __shared__ float lpart[4][2][32];
    __shared__ float obuf[4][32][33];

    int tid = threadIdx.x;
    int wv_ = __builtin_amdgcn_readfirstlane(tid >> 6);
    int lane = tid & 63;
    int l31 = lane & 31, lh = lane >> 5;
    bool hi = (lh != 0);
    int id = blockIdx.x;
    int cs = id & 1, b = (id >> 1) & 3, jt = id >> 3;
    int jbase = jt * 64, cb = cs * 128;

    const unsigned short* qbb = qb + (size_t)b * NN * C16;
    const unsigned short* kbb = kb + (size_t)b * NN * C16;
    const unsigned short* vbb = vb + ((size_t)b * CC + cb) * NN;

    short8 qf0 = *(const short8*)(qbb + (size_t)(jbase + l31) * C16 + lh * 8);
    short8 qf1 = *(const short8*)(qbb + (size_t)(jbase + 32 + l31) * C16 + lh * 8);

    floatx16 z16 = {0,0,0,0,0,0,0,0,0,0,0,0,0,0,0,0};
    int kw = wv_ * 1024;

    // ---- pre-pass: true row max over this wave's k-range (wrap-indexed, in-bounds) ----
    float mx0 = -INFINITY, mx1 = -INFINITY;
    {
        short8 a0 = *(const short8*)(kbb + (size_t)(kw + l31) * C16 + lh * 8);
        short8 a1 = *(const short8*)(kbb + (size_t)(kw + 32 + l31) * C16 + lh * 8);
#pragma unroll 1
        for (int s = 0; s < 32; s += 2) {
            floatx16 s0 = __builtin_amdgcn_mfma_f32_32x32x16_bf16(a0, qf0, z16, 0, 0, 0);
            floatx16 s1 = __builtin_amdgcn_mfma_f32_32x32x16_bf16(a0, qf1, z16, 0, 0, 0);
            a0 = *(const short8*)(kbb + (size_t)(kw + ((s + 2) & 31) * 32 + l31) * C16 + lh * 8);
            floatx16 s2 = __builtin_amdgcn_mfma_f32_32x32x16_bf16(a1, qf0, z16, 0, 0, 0);
            floatx16 s3 = __builtin_amdgcn_mfma_f32_32x32x16_bf16(a1, qf1, z16, 0, 0, 0);
            a1 = *(const short8*)(kbb + (size_t)(kw + ((s + 3) & 31) * 32 + l31) * C16 + lh * 8);
#pragma unroll
            for (int r = 0; r < 16; ++r) {
                mx0 = fmaxf(mx0, fmaxf(s0[r], s2[r]));
                mx1 = fmaxf(mx1, fmaxf(s1[r], s3[r]));
            }
        }
    }
    mx0 = fmaxf(mx0, __shfl_xor(mx0, 32, 64));
    mx1 = fmaxf(mx1, __shfl_xor(mx1, 32, 64));
    if (lh == 0) { mp[wv_][0][l31] = mx0; mp[wv_][1][l31] = mx1; }
    __syncthreads();
    float mneg0 = -fmaxf(fmaxf(mp[0][0][l31], mp[1][0][l31]),
                         fmaxf(mp[2][0][l31], mp[3][0][l31]));
    float mneg1 = -fmaxf(fmaxf(mp[0][1][l31], mp[1][1][l31]),
                         fmaxf(mp[2][1][l31], mp[3][1][l31]));

    // ---- main loop ----
    floatx16 acc0[4], acc1[4];
#pragma unroll
    for (int cg = 0; cg < 4; ++cg) { acc0[cg] = z16; acc1[cg] = z16; }
    float lsum0 = 0.f, lsum1 = 0.f;

    const unsigned short* vp0 = vbb + (size_t)l31 * NN + kw + lh * 8;
    const unsigned short* vp1 = vp0 + (size_t)32 * NN;
    const unsigned short* vp2 = vp0 + (size_t)64 * NN;
    const unsigned short* vp3 = vp0 + (size_t)96 * NN;

    short8 ak = *(const short8*)(kbb + (size_t)(kw + l31) * C16 + lh * 8);
#pragma unroll 1
    for (int step = 0; step < 32; ++step) {
        // V loads issued first — latency hidden behind S-MFMA + packs
        short8 vf0a = *(const short8*)vp0, vf0b = *(const short8*)(vp0 + 16);
        short8 vf1a = *(const short8*)vp1, vf1b = *(const short8*)(vp1 + 16);
        short8 vf2a = *(const short8*)vp2, vf2b = *(const short8*)(vp2 + 16);
        short8 vf3a = *(const short8*)vp3, vf3b = *(const short8*)(vp3 + 16);
        floatx16 sc0 = __builtin_amdgcn_mfma_f32_32x32x16_bf16(ak, qf0, z16, 0, 0, 0);
        floatx16 sc1 = __builtin_amdgcn_mfma_f32_32x32x16_bf16(ak, qf1, z16, 0, 0, 0);
        ak = *(const short8*)(kbb + (size_t)(kw + ((step + 1) & 31) * 32 + l31) * C16 + lh * 8);
        short8 A00, A01, A10, A11;
        pack_p(sc0, mneg0, hi, &A00, &A01, &lsum0);
        pack_p(sc1, mneg1, hi, &A10, &A11, &lsum1);
        acc0[0] = __builtin_amdgcn_mfma_f32_32x32x16_bf16(A00, vf0a, acc0[0], 0, 0, 0);
        acc0[0] = __builtin_amdgcn_mfma_f32_32x32x16_bf16(A01, vf0b, acc0[0], 0, 0, 0);
        acc1[0] = __builtin_amdgcn_mfma_f32_32x32x16_bf16(A10, vf0a, acc1[0], 0, 0, 0);
        acc1[0] = __builtin_amdgcn_mfma_f32_32x32x16_bf16(A11, vf0b, acc1[0], 0, 0, 0);
        acc0[1] = __builtin_amdgcn_mfma_f32_32x32x16_bf16(A00, vf1a, acc0[1], 0, 0, 0);
        acc0[1] = __builtin_amdgcn_mfma_f32_32x32x16_bf16(A01, vf1b, acc0[1], 0, 0, 0);
        acc1[1] = __builtin_amdgcn_mfma_f32_32x32x16_bf16(A10, vf1a, acc1[1], 0, 0, 0);
        acc1[1] = __builtin_amdgcn_mfma_f32_32x32x16_bf16(A11, vf1b, acc1[1], 0, 0, 0);
        acc0[2] = __builtin_amdgcn_mfma_f32_32x32x16_bf16(A00, vf2a, acc0[2], 0, 0, 0);
        acc0[2] = __builtin_amdgcn_mfma_f32_32x32x16_bf16(A01, vf2b, acc0[2], 0, 0, 0);
        acc1[2] = __builtin_amdgcn_mfma_f32_32x32x16_bf16(A10, vf2a, acc1[2], 0, 0, 0);
        acc1[2] = __builtin_amdgcn_mfma_f32_32x32x16_bf16(A11, vf2b, acc1[2], 0, 0, 0);
        acc0[3] = __builtin_amdgcn_mfma_f32_32x32x16_bf16(A00, vf3a, acc0[3], 0, 0, 0);
        acc0[3] = __builtin_amdgcn_mfma_f32_32x32x16_bf16(A01, vf3b, acc0[3], 0, 0, 0);
        acc1[3] = __builtin_amdgcn_mfma_f32_32x32x16_bf16(A10, vf3a, acc1[3], 0, 0, 0);
        acc1[3] = __builtin_amdgcn_mfma_f32_32x32x16_bf16(A11, vf3b, acc1[3], 0, 0, 0);
        vp0 += 32; vp1 += 32; vp2 += 32; vp3 += 32;
    }

    // l partials: combine lane halves (disjoint kcols), publish per wave
    lsum0 += __shfl_xor(lsum0, 32, 64);
    lsum1 += __shfl_xor(lsum1, 32, 64);
    if (lh == 0) { lpart[wv_][0][l31] = lsum0; lpart[wv_][1][l31] = lsum1; }
    __syncthreads();

    int j31 = tid & 31;
    float gamma = gamma_p[0];
    float gl0 = gamma / (lpart[0][0][j31] + lpart[1][0][j31] + lpart[2][0][j31] + lpart[3][0][j31]);
    float gl1 = gamma / (lpart[0][1][j31] + lpart[1][1][j31] + lpart[2][1][j31] + lpart[3][1][j31]);
    const float* xbb = x + (size_t)b * CC * NN;
    float* obb = out + (size_t)b * CC * NN;
    int hofs = lh * 4;
    int cgrp = tid >> 5;   // 0..7 -> 4 c-rows each
    // O reduction over waves, one (jg, cg) 32x32 tile at a time
    // acc C-layout: col(lane&31)=c-local, row=j-local; write obuf[w][j][c], read obuf[w][j31][c]
#pragma unroll
    for (int jg = 0; jg < 2; ++jg) {
        float gl = jg ? gl1 : gl0;
#pragma unroll
        for (int cg = 0; cg < 4; ++cg) {
            __syncthreads();
            const floatx16& a = jg ? acc1[cg] : acc0[cg];
#pragma unroll
            for (int r = 0; r < 16; ++r) {
                int row = (r & 3) + 8 * (r >> 2) + hofs;
                obuf[wv_][row][l31] = a[r];
            }
            __syncthreads();
#pragma unroll
            for (int i = 0; i < 4; ++i) {
                int c = cgrp * 4 + i;
                float val = obuf[0][j31][c] + obuf[1][j31][c] + obuf[2][j31][c] + obuf[3][j31][c];
                size_t oidx = (size_t)(cb + cg * 32 + c) * NN + jbase + jg * 32 + j31;
                obb[oidx] = fmaf(gl, val, xbb[oidx]);
            }
        }
    }
}

extern "C" void kernel_launch(void* const* d_in, const int* in_sizes, int n_in,
                              void* d_out, int out_size, void* d_ws, size_t ws_size,
                              hipStream_t stream) {
    const float* x     = (const float*)d_in[0];
    const float* wq    = (const float*)d_in[1];
    const float* bq    = (const float*)d_in[2];
    const float* wk    = (const float*)d_in[3];
    const float* bk    = (const float*)d_in[4];
    const float* wv    = (const float*)d_in[5];
    const float* bv    = (const float*)d_in[6];
    const float* gamma = (const float*)d_in[7];
    const float* eps_q = (const float*)d_in[8];
    const float* eps_k = (const float*)d_in[9];
    float* out = (float*)d_out;

    char* ws = (char*)d_ws;
    float* qraw = (float*)ws;                                        // 1 MB
    float* kraw = (float*)(ws + (1u << 20));                         // 1 MB
    float* nu2  = (float*)(ws + (2u << 20));                         // 512 B
    unsigned short* qb = (unsigned short*)(ws + (2u << 20) + 4096);  // 512 KB
    unsigned short* kb = qb + (size_t)NB * NN * C16;                 // 512 KB
    unsigned short* vb = kb + (size_t)NB * NN * C16;                 // 8 MB
    unsigned short* xT = vb + (size_t)NB * CC * NN;                  // 8 MB
    unsigned short* wvb = xT + (size_t)NB * NN * CC;                 // 128 KB
    unsigned short* wqkb = wvb + (size_t)CC * CC;                    // 48 KB

    prep_kernel<<<dim3(1112), dim3(256), 0, stream>>>(x, wv, wq, wk, xT, wvb, wqkb, nu2);
    conv_kernel<<<dim3(768), dim3(256), 0, stream>>>(xT, wvb, wqkb, bv, bq, bk, vb, qraw, kraw, nu2);
    frn_mish_kernel<<<dim3(128), dim3(256), 0, stream>>>(qraw, kraw, nu2, eps_q, eps_k, qb, kb);
    attn_kernel<<<dim3(512), dim3(256), 0, stream>>>(qb, kb, vb, x, gamma, out);
}

// Round 10
// 198.445 us; speedup vs baseline: 1.3419x; 1.1183x over previous
//
#include <hip/hip_runtime.h>
#include <stdint.h>

#define NB 4
#define CC 256
#define C16 16
#define HH 64
#define WW 64
#define NN 4096

typedef __attribute__((ext_vector_type(8))) short short8;
typedef __attribute__((ext_vector_type(4))) float floatx4;
typedef __attribute__((ext_vector_type(16))) float floatx16;

#if __has_builtin(__builtin_amdgcn_exp2f)
#define EXP2(x) __builtin_amdgcn_exp2f(x)
#else
#define EXP2(x) exp2f(x)
#endif

__device__ __forceinline__ unsigned short f2bf(float f) {
    union { float f; unsigned u; } v; v.f = f;
    unsigned r = v.u + 0x7fffu + ((v.u >> 16) & 1u);
    return (unsigned short)(r >> 16);
}

// Fragment-major layouts (frag = 32 rows x 16 k = 64 lanes x 8 bf16 = 1KB):
//   qb/kb: frag f = b*128 + (n>>5); lane (l31=n&31, lh=o>>3) holds o = lh*8+i
//          addr = f*512 + (n&31 + 32*(o>>3))*8 + (o&7)
//   vb:    frag f = (b*8 + (c>>5))*256 + (n>>4); lane (l31=c&31, lh=(n>>3)&1)
//          addr = f*512 + (c&31 + 32*((n>>3)&1))*8 + (n&7)

// ========== K1: cast x->xT bf16 [b][n][c]; cast wv/wq/wk; zero nu2 ==========
__global__ __launch_bounds__(256) void prep_kernel(
        const float* __restrict__ x, const float* __restrict__ wv,
        const float* __restrict__ wq, const float* __restrict__ wk,
        unsigned short* __restrict__ xT, unsigned short* __restrict__ wvb,
        unsigned short* __restrict__ wqkb, float* __restrict__ nu2) {
    int bid = blockIdx.x;
    if (bid < 1024) {
        __shared__ float tile[64][65];
        int nt = bid & 63, ct = (bid >> 6) & 3, b = bid >> 8;
        int n0 = nt * 64, c0 = ct * 64;
        int ln = threadIdx.x & 63, grp = threadIdx.x >> 6;
        const float* xb = x + ((size_t)b * CC + c0) * NN + n0;
        for (int i = 0; i < 16; ++i) {
            int c = i * 4 + grp;
            tile[c][ln] = xb[(size_t)c * NN + ln];
        }
        __syncthreads();
        unsigned short* xtb = xT + ((size_t)b * NN + n0) * CC + c0;
        for (int i = 0; i < 16; ++i) {
            int n = i * 4 + grp;
            xtb[(size_t)n * CC + ln] = f2bf(tile[ln][n]);
        }
    } else {
        int idx = (bid - 1024) * 256 + threadIdx.x;
        if (bid == 1024 && threadIdx.x < 128) nu2[threadIdx.x] = 0.f;
        if (idx < 16384) {
            float4 v = *(const float4*)(wv + idx * 4);
            ushort4 o;
            o.x = f2bf(v.x); o.y = f2bf(v.y); o.z = f2bf(v.z); o.w = f2bf(v.w);
            *(ushort4*)(wvb + idx * 4) = o;
        } else if (idx < 16384 + 6144) {
            int base = (idx - 16384) * 4;
#pragma unroll
            for (int u = 0; u < 4; ++u) {
                int e = base + u;
                int t = e / 12288;
                int i = e - t * 12288;
                int tap = i >> 12, o = (i >> 8) & 15, c = i & 255;
                const float* src = t ? wk : wq;
                wqkb[e] = f2bf(src[o * 768 + c * 3 + tap]);
            }
        }
    }
}

// ========== K2: conv_v (blocks 0..511) + conv_qk w/ fused FRN-ssq atomics ==========
__global__ __launch_bounds__(256) void conv_kernel(
        const unsigned short* __restrict__ xT, const unsigned short* __restrict__ wvb,
        const unsigned short* __restrict__ wqkb, const float* __restrict__ bv,
        const float* __restrict__ bq, const float* __restrict__ bk,
        unsigned short* __restrict__ vb, float* __restrict__ qraw,
        float* __restrict__ kraw, float* __restrict__ nu2) {
    int bid = blockIdx.x;
    int tid = threadIdx.x;
    int wv_ = tid >> 6, lane = tid & 63;
    int q16 = lane >> 4, c16 = lane & 15;
    if (bid < 512) {
        int ntile = bid & 63, b = (bid >> 6) & 3, ch = bid >> 8;
        int n0 = ntile * 64;
        int cb = ch * 128 + wv_ * 32;
        floatx4 fzero = {0.f, 0.f, 0.f, 0.f};
        floatx4 acc[2][4];
        for (int ct = 0; ct < 2; ++ct)
            for (int nt = 0; nt < 4; ++nt) acc[ct][nt] = fzero;
        const unsigned short* xb = xT + ((size_t)b * NN + n0) * CC;
        for (int kc = 0; kc < 8; ++kc) {
            int ko = kc * 32 + q16 * 8;
            short8 a0 = *(const short8*)(wvb + (size_t)(cb + c16) * CC + ko);
            short8 a1 = *(const short8*)(wvb + (size_t)(cb + 16 + c16) * CC + ko);
            short8 bf[4];
#pragma unroll
            for (int nt = 0; nt < 4; ++nt)
                bf[nt] = *(const short8*)(xb + (size_t)(nt * 16 + c16) * CC + ko);
#pragma unroll
            for (int nt = 0; nt < 4; ++nt) {
                acc[0][nt] = __builtin_amdgcn_mfma_f32_16x16x32_bf16(a0, bf[nt], acc[0][nt], 0, 0, 0);
                acc[1][nt] = __builtin_amdgcn_mfma_f32_16x16x32_bf16(a1, bf[nt], acc[1][nt], 0, 0, 0);
            }
        }
        // store in V-frag-major layout
#pragma unroll
        for (int ct = 0; ct < 2; ++ct)
            for (int nt = 0; nt < 4; ++nt)
                for (int r = 0; r < 4; ++r) {
                    int c = cb + ct * 16 + q16 * 4 + r;
                    int n = n0 + nt * 16 + c16;
                    size_t addr = (((size_t)b * 8 + (c >> 5)) * 256 + (n >> 4)) * 512
                                + ((c & 31) + 32 * ((n >> 3) & 1)) * 8 + (n & 7);
                    vb[addr] = f2bf(acc[ct][nt][r] + bv[c]);
                }
    } else {
        int cv = bid - 512;
        int nb = cv & 63, b = cv >> 6;
        int n = nb * 64 + wv_ * 16 + c16;
        int h = n >> 6, w = n & 63;
        bool vm1 = (w != 0), vp1 = (w != 63);
        bool vm64 = (h != 0), vp64 = (h != 63);
        short8 zero8 = {0, 0, 0, 0, 0, 0, 0, 0};
        floatx4 accq = {0.f, 0.f, 0.f, 0.f}, acck = {0.f, 0.f, 0.f, 0.f};
        const unsigned short* xb = xT + (size_t)b * NN * CC;
        const unsigned short* wrow = wqkb + c16 * 256;
        for (int kc = 0; kc < 8; ++kc) {
            int ko = kc * 32 + q16 * 8;
            short8 b0 = *(const short8*)(xb + (size_t)n * CC + ko);
            short8 bm1 = vm1 ? *(const short8*)(xb + (size_t)(n - 1) * CC + ko) : zero8;
            short8 bp1 = vp1 ? *(const short8*)(xb + (size_t)(n + 1) * CC + ko) : zero8;
            short8 bm64 = vm64 ? *(const short8*)(xb + (size_t)(n - 64) * CC + ko) : zero8;
            short8 bp64 = vp64 ? *(const short8*)(xb + (size_t)(n + 64) * CC + ko) : zero8;
            short8 aq0 = *(const short8*)(wrow + 0 * 4096 + ko);
            short8 aq1 = *(const short8*)(wrow + 1 * 4096 + ko);
            short8 aq2 = *(const short8*)(wrow + 2 * 4096 + ko);
            short8 ak0 = *(const short8*)(wrow + 12288 + 0 * 4096 + ko);
            short8 ak1 = *(const short8*)(wrow + 12288 + 1 * 4096 + ko);
            short8 ak2 = *(const short8*)(wrow + 12288 + 2 * 4096 + ko);
            accq = __builtin_amdgcn_mfma_f32_16x16x32_bf16(aq0, bm1, accq, 0, 0, 0);
            accq = __builtin_amdgcn_mfma_f32_16x16x32_bf16(aq1, b0, accq, 0, 0, 0);
            accq = __builtin_amdgcn_mfma_f32_16x16x32_bf16(aq2, bp1, accq, 0, 0, 0);
            acck = __builtin_amdgcn_mfma_f32_16x16x32_bf16(ak0, bm64, acck, 0, 0, 0);
            acck = __builtin_amdgcn_mfma_f32_16x16x32_bf16(ak1, b0, acck, 0, 0, 0);
            acck = __builtin_amdgcn_mfma_f32_16x16x32_bf16(ak2, bp64, acck, 0, 0, 0);
        }
        float sq[4], sk[4];
#pragma unroll
        for (int r = 0; r < 4; ++r) {
            int o = q16 * 4 + r;
            float vq = accq[r] + bq[o];
            float vk = acck[r] + bk[o];
            qraw[(size_t)(b * C16 + o) * NN + n] = vq;
            kraw[(size_t)(b * C16 + o) * NN + n] = vk;
            sq[r] = vq * vq; sk[r] = vk * vk;
        }
#pragma unroll
        for (int r = 0; r < 4; ++r) {
#pragma unroll
            for (int off = 1; off < 16; off <<= 1) {
                sq[r] += __shfl_xor(sq[r], off, 64);
                sk[r] += __shfl_xor(sk[r], off, 64);
            }
        }
        if (c16 == 0) {
#pragma unroll
            for (int r = 0; r < 4; ++r) {
                int o = q16 * 4 + r;
                atomicAdd(nu2 + b * C16 + o, sq[r]);
                atomicAdd(nu2 + 64 + b * C16 + o, sk[r]);
            }
        }
    }
}

// ========== K3: FRN + Mish, write bf16 Q/K in frag-major layout ==========
// q additionally scaled by log2(e) so attention can use exp2.
__global__ __launch_bounds__(256) void frn_mish_kernel(
        const float* __restrict__ qraw, const float* __restrict__ kraw,
        const float* __restrict__ nu2, const float* __restrict__ eps_q,
        const float* __restrict__ eps_k, unsigned short* __restrict__ qb,
        unsigned short* __restrict__ kb) {
    int blk = blockIdx.x;
    int tensor = blk >> 6;
    int b = (blk >> 4) & 3;
    int ch = blk & 15;
    const float* raw = tensor ? kraw : qraw;
    const float* eps = tensor ? eps_k : eps_q;
    unsigned short* outp = tensor ? kb : qb;
    const float* nu = nu2 + tensor * 64 + b * C16;
    float scale = tensor ? 1.0f : 1.44269504f;
    int n = ch * 256 + threadIdx.x;
    union { unsigned short s[16]; uint4 u[2]; } pk;
    for (int o = 0; o < C16; ++o) {
        float r = raw[(size_t)(b * C16 + o) * NN + n];
        float v = r * rsqrtf(nu[o] * (1.f / (float)NN) + fabsf(eps[o]));
        float sp = fmaxf(v, 0.f) + log1pf(expf(-fabsf(v)));   // stable softplus
        pk.s[o] = f2bf(v * tanhf(sp) * scale);
    }
    size_t base = ((size_t)b * 128 + (n >> 5)) * 512 + (size_t)(n & 31) * 8;
    *(uint4*)(outp + base)       = pk.u[0];   // o = 0..7  (lh=0)
    *(uint4*)(outp + base + 256) = pk.u[1];   // o = 8..15 (lh=1)
}

// exp2 + pack to bf16 A-frags (half-lane exchange); lsum accumulated
__device__ __forceinline__ void pack_p(
        floatx16 sc, float mneg, bool hi, short8* A0, short8* A1, float* lsum) {
    unsigned pk[8];
    float ls = 0.f;
#pragma unroll
    for (int p = 0; p < 8; ++p) {
        float e0 = EXP2(sc[2 * p] + mneg);
        float e1 = EXP2(sc[2 * p + 1] + mneg);
        ls += e0 + e1;
        pk[p] = __builtin_amdgcn_perm(__float_as_uint(e1), __float_as_uint(e0), 0x07060302u);
    }
    *lsum += ls;
    unsigned xk[8];
#pragma unroll
    for (int p = 0; p < 8; ++p) xk[p] = (unsigned)__shfl_xor((int)pk[p], 32, 64);
    union { unsigned u[4]; short8 s; } a0, a1;
    a0.u[0] = hi ? xk[2] : pk[0]; a0.u[1] = hi ? xk[3] : pk[1];
    a0.u[2] = hi ? pk[2] : xk[0]; a0.u[3] = hi ? pk[3] : xk[1];
    a1.u[0] = hi ? xk[6] : pk[4]; a1.u[1] = hi ? xk[7] : pk[5];
    a1.u[2] = hi ? pk[6] : xk[4]; a1.u[3] = hi ? pk[7] : xk[5];
    *A0 = a0.s; *A1 = a1.s;
}

// ========== K4: attention, j=64 c=128 per block, all loads frag-coalesced ==========
// grid 512: cs = id&1 (128-c), b = (id>>1)&3, jt = id>>3. 2 blocks/CU.
// Wave w streams k in [1024w, 1024w+1024) in 32-k steps.
__global__ __launch_bounds__(256, 2) void attn_kernel(
        const unsigned short* __restrict__ qb, const unsigned short* __restrict__ kb,
        const unsigned short* __restrict__ vb, const float* __restrict__ x,
        const float* __restrict__ gamma_p, float* __restrict__ out) {
    __shared__ float mp[4][2][32];
    __shared__ float lpart[4][2][32];
    __shared__ float obuf[4][32][33];

    int tid = threadIdx.x;
    int wv_ = __builtin_amdgcn_readfirstlane(tid >> 6);
    int lane = tid & 63;
    int l31 = lane & 31, lh = lane >> 5;
    bool hi = (lh != 0);
    int id = blockIdx.x;
    int cs = id & 1, b = (id >> 1) & 3, jt = id >> 3;
    int jbase = jt * 64, cb = cs * 128;
    int lane8 = lane * 8;

    // frag-major bases
    const unsigned short* qfb = qb + ((size_t)b * 128 + (jbase >> 5)) * 512 + lane8;
    const unsigned short* kfb = kb + ((size_t)b * 128 + (wv_ * 32)) * 512 + lane8;  // frag (kw>>5)

    short8 qf0 = *(const short8*)qfb;
    short8 qf1 = *(const short8*)(qfb + 512);

    floatx16 z16 = {0,0,0,0,0,0,0,0,0,0,0,0,0,0,0,0};

    // ---- pre-pass: true row max over this wave's k-range, 4-frag lookahead ----
    float mx0 = -INFINITY, mx1 = -INFINITY;
    {
        short8 ka[4];
#pragma unroll
        for (int t = 0; t < 4; ++t)
            ka[t] = *(const short8*)(kfb + (size_t)t * 512);
#pragma unroll 4
        for (int s = 0; s < 32; ++s) {
            short8 a = ka[s & 3];
            floatx16 s0 = __builtin_amdgcn_mfma_f32_32x32x16_bf16(a, qf0, z16, 0, 0, 0);
            floatx16 s1 = __builtin_amdgcn_mfma_f32_32x32x16_bf16(a, qf1, z16, 0, 0, 0);
            ka[s & 3] = *(const short8*)(kfb + (size_t)((s + 4) & 31) * 512);
#pragma unroll
            for (int r = 0; r < 16; ++r) {
                mx0 = fmaxf(mx0, s0[r]);
                mx1 = fmaxf(mx1, s1[r]);
            }
        }
    }
    mx0 = fmaxf(mx0, __shfl_xor(mx0, 32, 64));
    mx1 = fmaxf(mx1, __shfl_xor(mx1, 32, 64));
    if (lh == 0) { mp[wv_][0][l31] = mx0; mp[wv_][1][l31] = mx1; }
    __syncthreads();
    float mneg0 = -fmaxf(fmaxf(mp[0][0][l31], mp[1][0][l31]),
                         fmaxf(mp[2][0][l31], mp[3][0][l31]));
    float mneg1 = -fmaxf(fmaxf(mp[0][1][l31], mp[1][1][l31]),
                         fmaxf(mp[2][1][l31], mp[3][1][l31]));

    // ---- main loop ----
    floatx16 acc0[4], acc1[4];
#pragma unroll
    for (int cg = 0; cg < 4; ++cg) { acc0[cg] = z16; acc1[cg] = z16; }
    float lsum0 = 0.f, lsum1 = 0.f;

    // V frag pointers: ck = cs*4+cg, frag = (b*8+ck)*256 + (kw>>4); +1024 shorts/step
    const unsigned short* vp0 = vb + (((size_t)b * 8 + cs * 4 + 0) * 256 + wv_ * 64) * 512 + lane8;
    const unsigned short* vp1 = vb + (((size_t)b * 8 + cs * 4 + 1) * 256 + wv_ * 64) * 512 + lane8;
    const unsigned short* vp2 = vb + (((size_t)b * 8 + cs * 4 + 2) * 256 + wv_ * 64) * 512 + lane8;
    const unsigned short* vp3 = vb + (((size_t)b * 8 + cs * 4 + 3) * 256 + wv_ * 64) * 512 + lane8;

    short8 ak = *(const short8*)kfb;
#pragma unroll 1
    for (int step = 0; step < 32; ++step) {
        // V loads issued first — coalesced 1KB frags, hidden behind S-MFMA + packs
        short8 vf0a = *(const short8*)vp0, vf0b = *(const short8*)(vp0 + 512);
        short8 vf1a = *(const short8*)vp1, vf1b = *(const short8*)(vp1 + 512);
        short8 vf2a = *(const short8*)vp2, vf2b = *(const short8*)(vp2 + 512);
        short8 vf3a = *(const short8*)vp3, vf3b = *(const short8*)(vp3 + 512);
        floatx16 sc0 = __builtin_amdgcn_mfma_f32_32x32x16_bf16(ak, qf0, z16, 0, 0, 0);
        floatx16 sc1 = __builtin_amdgcn_mfma_f32_32x32x16_bf16(ak, qf1, z16, 0, 0, 0);
        ak = *(const short8*)(kfb + (size_t)((step + 1) & 31) * 512);
        short8 A00, A01, A10, A11;
        pack_p(sc0, mneg0, hi, &A00, &A01, &lsum0);
        pack_p(sc1, mneg1, hi, &A10, &A11, &lsum1);
        acc0[0] = __builtin_amdgcn_mfma_f32_32x32x16_bf16(A00, vf0a, acc0[0], 0, 0, 0);
        acc0[0] = __builtin_amdgcn_mfma_f32_32x32x16_bf16(A01, vf0b, acc0[0], 0, 0, 0);
        acc1[0] = __builtin_amdgcn_mfma_f32_32x32x16_bf16(A10, vf0a, acc1[0], 0, 0, 0);
        acc1[0] = __builtin_amdgcn_mfma_f32_32x32x16_bf16(A11, vf0b, acc1[0], 0, 0, 0);
        acc0[1] = __builtin_amdgcn_mfma_f32_32x32x16_bf16(A00, vf1a, acc0[1], 0, 0, 0);
        acc0[1] = __builtin_amdgcn_mfma_f32_32x32x16_bf16(A01, vf1b, acc0[1], 0, 0, 0);
        acc1[1] = __builtin_amdgcn_mfma_f32_32x32x16_bf16(A10, vf1a, acc1[1], 0, 0, 0);
        acc1[1] = __builtin_amdgcn_mfma_f32_32x32x16_bf16(A11, vf1b, acc1[1], 0, 0, 0);
        acc0[2] = __builtin_amdgcn_mfma_f32_32x32x16_bf16(A00, vf2a, acc0[2], 0, 0, 0);
        acc0[2] = __builtin_amdgcn_mfma_f32_32x32x16_bf16(A01, vf2b, acc0[2], 0, 0, 0);
        acc1[2] = __builtin_amdgcn_mfma_f32_32x32x16_bf16(A10, vf2a, acc1[2], 0, 0, 0);
        acc1[2] = __builtin_amdgcn_mfma_f32_32x32x16_bf16(A11, vf2b, acc1[2], 0, 0, 0);
        acc0[3] = __builtin_amdgcn_mfma_f32_32x32x16_bf16(A00, vf3a, acc0[3], 0, 0, 0);
        acc0[3] = __builtin_amdgcn_mfma_f32_32x32x16_bf16(A01, vf3b, acc0[3], 0, 0, 0);
        acc1[3] = __builtin_amdgcn_mfma_f32_32x32x16_bf16(A10, vf3a, acc1[3], 0, 0, 0);
        acc1[3] = __builtin_amdgcn_mfma_f32_32x32x16_bf16(A11, vf3b, acc1[3], 0, 0, 0);
        vp0 += 1024; vp1 += 1024; vp2 += 1024; vp3 += 1024;
    }

    // l partials: combine lane halves (disjoint kcols), publish per wave
    lsum0 += __shfl_xor(lsum0, 32, 64);
    lsum1 += __shfl_xor(lsum1, 32, 64);
    if (lh == 0) { lpart[wv_][0][l31] = lsum0; lpart[wv_][1][l31] = lsum1; }
    __syncthreads();

    int j31 = tid & 31;
    float gamma = gamma_p[0];
    float gl0 = gamma / (lpart[0][0][j31] + lpart[1][0][j31] + lpart[2][0][j31] + lpart[3][0][j31]);
    float gl1 = gamma / (lpart[0][1][j31] + lpart[1][1][j31] + lpart[2][1][j31] + lpart[3][1][j31]);
    const float* xbb = x + (size_t)b * CC * NN;
    float* obb = out + (size_t)b * CC * NN;
    int hofs = lh * 4;
    int cgrp = tid >> 5;   // 0..7 -> 4 c-rows each
    // O reduction over waves, one (jg, cg) 32x32 tile at a time
    // acc C-layout: col(lane&31)=c-local, row=j-local; write obuf[w][j][c], read obuf[w][j31][c]
#pragma unroll
    for (int jg = 0; jg < 2; ++jg) {
        float gl = jg ? gl1 : gl0;
#pragma unroll
        for (int cg = 0; cg < 4; ++cg) {
            __syncthreads();
            const floatx16& a = jg ? acc1[cg] : acc0[cg];
#pragma unroll
            for (int r = 0; r < 16; ++r) {
                int row = (r & 3) + 8 * (r >> 2) + hofs;
                obuf[wv_][row][l31] = a[r];
            }
            __syncthreads();
#pragma unroll
            for (int i = 0; i < 4; ++i) {
                int c = cgrp * 4 + i;
                float val = obuf[0][j31][c] + obuf[1][j31][c] + obuf[2][j31][c] + obuf[3][j31][c];
                size_t oidx = (size_t)(cb + cg * 32 + c) * NN + jbase + jg * 32 + j31;
                obb[oidx] = fmaf(gl, val, xbb[oidx]);
            }
        }
    }
}

extern "C" void kernel_launch(void* const* d_in, const int* in_sizes, int n_in,
                              void* d_out, int out_size, void* d_ws, size_t ws_size,
                              hipStream_t stream) {
    const float* x     = (const float*)d_in[0];
    const float* wq    = (const float*)d_in[1];
    const float* bq    = (const float*)d_in[2];
    const float* wk    = (const float*)d_in[3];
    const float* bk    = (const float*)d_in[4];
    const float* wv    = (const float*)d_in[5];
    const float* bv    = (const float*)d_in[6];
    const float* gamma = (const float*)d_in[7];
    const float* eps_q = (const float*)d_in[8];
    const float* eps_k = (const float*)d_in[9];
    float* out = (float*)d_out;

    char* ws = (char*)d_ws;
    float* qraw = (float*)ws;                                        // 1 MB
    float* kraw = (float*)(ws + (1u << 20));                         // 1 MB
    float* nu2  = (float*)(ws + (2u << 20));                         // 512 B
    unsigned short* qb = (unsigned short*)(ws + (2u << 20) + 4096);  // 512 KB
    unsigned short* kb = qb + (size_t)NB * NN * C16;                 // 512 KB
    unsigned short* vb = kb + (size_t)NB * NN * C16;                 // 8 MB
    unsigned short* xT = vb + (size_t)NB * CC * NN;                  // 8 MB
    unsigned short* wvb = xT + (size_t)NB * NN * CC;                 // 128 KB
    unsigned short* wqkb = wvb + (size_t)CC * CC;                    // 48 KB

    prep_kernel<<<dim3(1112), dim3(256), 0, stream>>>(x, wv, wq, wk, xT, wvb, wqkb, nu2);
    conv_kernel<<<dim3(768), dim3(256), 0, stream>>>(xT, wvb, wqkb, bv, bq, bk, vb, qraw, kraw, nu2);
    frn_mish_kernel<<<dim3(128), dim3(256), 0, stream>>>(qraw, kraw, nu2, eps_q, eps_k, qb, kb);
    attn_kernel<<<dim3(512), dim3(256), 0, stream>>>(qb, kb, vb, x, gamma, out);
}

// Round 11
// 183.490 us; speedup vs baseline: 1.4513x; 1.0815x over previous
//
#include <hip/hip_runtime.h>
#include <stdint.h>

#define NB 4
#define CC 256
#define C16 16
#define HH 64
#define WW 64
#define NN 4096

typedef __attribute__((ext_vector_type(8))) short short8;
typedef __attribute__((ext_vector_type(4))) float floatx4;
typedef __attribute__((ext_vector_type(16))) float floatx16;

#if __has_builtin(__builtin_amdgcn_exp2f)
#define EXP2(x) __builtin_amdgcn_exp2f(x)
#else
#define EXP2(x) exp2f(x)
#endif

__device__ __forceinline__ unsigned short f2bf(float f) {
    union { float f; unsigned u; } v; v.f = f;
    unsigned r = v.u + 0x7fffu + ((v.u >> 16) & 1u);
    return (unsigned short)(r >> 16);
}
__device__ __forceinline__ float bf2f(unsigned short h) {
    union { unsigned u; float f; } v; v.u = (unsigned)h << 16;
    return v.f;
}

// Fragment-major layouts (frag = 32 rows x 16 k = 64 lanes x 8 bf16 = 1KB):
//   qb/kb: frag f = b*128 + (n>>5); addr = f*512 + (n&31 + 32*(o>>3))*8 + (o&7)
//   vb:    frag f = (b*8 + (c>>5))*256 + (n>>4); addr = f*512 + (c&31 + 32*((n>>3)&1))*8 + (n&7)

// ========== K1: cast x->xT bf16 [b][n][c] (vectorized); cast wv/wq/wk; zero nu2 ==========
__global__ __launch_bounds__(256) void prep_kernel(
        const float* __restrict__ x, const float* __restrict__ wv,
        const float* __restrict__ wq, const float* __restrict__ wk,
        unsigned short* __restrict__ xT, unsigned short* __restrict__ wvb,
        unsigned short* __restrict__ wqkb, float* __restrict__ nu2) {
    int bid = blockIdx.x;
    if (bid < 1024) {
        __shared__ float tile_t[64][65];   // [n-local][c-local], pad 65: 2-way free
        int nt = bid & 63, ct = (bid >> 6) & 3, b = bid >> 8;
        int n0 = nt * 64, c0 = ct * 64;
        int tid = threadIdx.x;
        int rg = tid >> 4, f = tid & 15;
        const float* xb = x + ((size_t)b * CC + c0) * NN + n0;
#pragma unroll
        for (int p = 0; p < 4; ++p) {
            int c = p * 16 + rg;
            float4 v = *(const float4*)(xb + (size_t)c * NN + f * 4);
            tile_t[f * 4 + 0][c] = v.x;
            tile_t[f * 4 + 1][c] = v.y;
            tile_t[f * 4 + 2][c] = v.z;
            tile_t[f * 4 + 3][c] = v.w;
        }
        __syncthreads();
        unsigned short* xtb = xT + ((size_t)b * NN + n0) * CC + c0;
#pragma unroll
        for (int p = 0; p < 4; ++p) {
            int n = p * 16 + rg;
            ushort4 st;
            st.x = f2bf(tile_t[n][f * 4 + 0]);
            st.y = f2bf(tile_t[n][f * 4 + 1]);
            st.z = f2bf(tile_t[n][f * 4 + 2]);
            st.w = f2bf(tile_t[n][f * 4 + 3]);
            *(ushort4*)(xtb + (size_t)n * CC + f * 4) = st;
        }
    } else {
        int idx = (bid - 1024) * 256 + threadIdx.x;
        if (bid == 1024 && threadIdx.x < 128) nu2[threadIdx.x] = 0.f;
        if (idx < 16384) {
            float4 v = *(const float4*)(wv + idx * 4);
            ushort4 o;
            o.x = f2bf(v.x); o.y = f2bf(v.y); o.z = f2bf(v.z); o.w = f2bf(v.w);
            *(ushort4*)(wvb + idx * 4) = o;
        } else if (idx < 16384 + 6144) {
            int base = (idx - 16384) * 4;
#pragma unroll
            for (int u = 0; u < 4; ++u) {
                int e = base + u;
                int t = e / 12288;
                int i = e - t * 12288;
                int tap = i >> 12, o = (i >> 8) & 15, c = i & 255;
                const float* src = t ? wk : wq;
                wqkb[e] = f2bf(src[o * 768 + c * 3 + tap]);
            }
        }
    }
}

// ========== K2: conv_v (0..511) + conv_qk w/ FRN-ssq atomics (512..767) ==========
// Both use SWAPPED MFMA operands (A = x-frag, B = weight-frag) so each lane's C
// holds 4 consecutive n -> vectorized stores.
__global__ __launch_bounds__(256) void conv_kernel(
        const unsigned short* __restrict__ xT, const unsigned short* __restrict__ wvb,
        const unsigned short* __restrict__ wqkb, const float* __restrict__ bv,
        const float* __restrict__ bq, const float* __restrict__ bk,
        unsigned short* __restrict__ vb, unsigned short* __restrict__ qrawh,
        unsigned short* __restrict__ krawh, float* __restrict__ nu2) {
    int bid = blockIdx.x;
    int tid = threadIdx.x;
    int wv_ = tid >> 6, lane = tid & 63;
    int q16 = lane >> 4, c16 = lane & 15;
    if (bid < 512) {
        int ntile = bid & 63, b = (bid >> 6) & 3, ch = bid >> 8;
        int n0 = ntile * 64;
        int cb = ch * 128 + wv_ * 32;
        floatx4 fzero = {0.f, 0.f, 0.f, 0.f};
        floatx4 acc[2][4];
        for (int ct = 0; ct < 2; ++ct)
            for (int nt = 0; nt < 4; ++nt) acc[ct][nt] = fzero;
        const unsigned short* xb = xT + ((size_t)b * NN + n0) * CC;
        for (int kc = 0; kc < 8; ++kc) {
            int ko = kc * 32 + q16 * 8;
            short8 a0 = *(const short8*)(wvb + (size_t)(cb + c16) * CC + ko);
            short8 a1 = *(const short8*)(wvb + (size_t)(cb + 16 + c16) * CC + ko);
            short8 bf[4];
#pragma unroll
            for (int nt = 0; nt < 4; ++nt)
                bf[nt] = *(const short8*)(xb + (size_t)(nt * 16 + c16) * CC + ko);
#pragma unroll
            for (int nt = 0; nt < 4; ++nt) {
                acc[0][nt] = __builtin_amdgcn_mfma_f32_16x16x32_bf16(bf[nt], a0, acc[0][nt], 0, 0, 0);
                acc[1][nt] = __builtin_amdgcn_mfma_f32_16x16x32_bf16(bf[nt], a1, acc[1][nt], 0, 0, 0);
            }
        }
        // C: row = q16*4+r -> n-local, col = c16 -> c-local. ushort4 frag-major stores.
        float bv0 = bv[cb + c16], bv1 = bv[cb + 16 + c16];
        int off = 32 * 8 * (q16 >> 1) + (q16 & 1) * 4 + c16 * 8;
#pragma unroll
        for (int ct = 0; ct < 2; ++ct) {
            float bvv = ct ? bv1 : bv0;
#pragma unroll
            for (int nt = 0; nt < 4; ++nt) {
                size_t fb = (((size_t)b * 8 + ch * 4 + wv_) * 256 + (n0 >> 4) + nt) * 512;
                ushort4 st;
                st.x = f2bf(acc[ct][nt][0] + bvv);
                st.y = f2bf(acc[ct][nt][1] + bvv);
                st.z = f2bf(acc[ct][nt][2] + bvv);
                st.w = f2bf(acc[ct][nt][3] + bvv);
                *(ushort4*)(vb + fb + off + ct * 16 * 8) = st;
            }
        }
    } else {
        int cv = bid - 512;
        int nb2 = cv & 63, b = cv >> 6;
        int nl = nb2 * 64 + wv_ * 16 + c16;     // load-n (A-frag m index)
        int h = nl >> 6, w = nl & 63;
        bool vm1 = (w != 0), vp1 = (w != 63);
        bool vm64 = (h != 0), vp64 = (h != 63);
        short8 zero8 = {0, 0, 0, 0, 0, 0, 0, 0};
        floatx4 accq = {0.f, 0.f, 0.f, 0.f}, acck = {0.f, 0.f, 0.f, 0.f};
        const unsigned short* xb = xT + (size_t)b * NN * CC;
        const unsigned short* wrow = wqkb + c16 * 256;
        for (int kc = 0; kc < 8; ++kc) {
            int ko = kc * 32 + q16 * 8;
            short8 b0 = *(const short8*)(xb + (size_t)nl * CC + ko);
            short8 bm1 = vm1 ? *(const short8*)(xb + (size_t)(nl - 1) * CC + ko) : zero8;
            short8 bp1 = vp1 ? *(const short8*)(xb + (size_t)(nl + 1) * CC + ko) : zero8;
            short8 bm64 = vm64 ? *(const short8*)(xb + (size_t)(nl - 64) * CC + ko) : zero8;
            short8 bp64 = vp64 ? *(const short8*)(xb + (size_t)(nl + 64) * CC + ko) : zero8;
            short8 aq0 = *(const short8*)(wrow + 0 * 4096 + ko);
            short8 aq1 = *(const short8*)(wrow + 1 * 4096 + ko);
            short8 aq2 = *(const short8*)(wrow + 2 * 4096 + ko);
            short8 ak0 = *(const short8*)(wrow + 12288 + 0 * 4096 + ko);
            short8 ak1 = *(const short8*)(wrow + 12288 + 1 * 4096 + ko);
            short8 ak2 = *(const short8*)(wrow + 12288 + 2 * 4096 + ko);
            accq = __builtin_amdgcn_mfma_f32_16x16x32_bf16(bm1, aq0, accq, 0, 0, 0);
            accq = __builtin_amdgcn_mfma_f32_16x16x32_bf16(b0, aq1, accq, 0, 0, 0);
            accq = __builtin_amdgcn_mfma_f32_16x16x32_bf16(bp1, aq2, accq, 0, 0, 0);
            acck = __builtin_amdgcn_mfma_f32_16x16x32_bf16(bm64, ak0, acck, 0, 0, 0);
            acck = __builtin_amdgcn_mfma_f32_16x16x32_bf16(b0, ak1, acck, 0, 0, 0);
            acck = __builtin_amdgcn_mfma_f32_16x16x32_bf16(bp64, ak2, acck, 0, 0, 0);
        }
        // C: row = q16*4+r -> n, col = c16 -> o. bf16 ushort4 stores.
        int nst = nb2 * 64 + wv_ * 16 + q16 * 4;
        float bqv = bq[c16], bkv = bk[c16];
        ushort4 sq4, sk4;
        float ssq = 0.f, ssk = 0.f;
        {
            float vq0 = accq[0] + bqv, vq1 = accq[1] + bqv, vq2 = accq[2] + bqv, vq3 = accq[3] + bqv;
            float vk0 = acck[0] + bkv, vk1 = acck[1] + bkv, vk2 = acck[2] + bkv, vk3 = acck[3] + bkv;
            sq4.x = f2bf(vq0); sq4.y = f2bf(vq1); sq4.z = f2bf(vq2); sq4.w = f2bf(vq3);
            sk4.x = f2bf(vk0); sk4.y = f2bf(vk1); sk4.z = f2bf(vk2); sk4.w = f2bf(vk3);
            ssq = vq0 * vq0 + vq1 * vq1 + vq2 * vq2 + vq3 * vq3;
            ssk = vk0 * vk0 + vk1 * vk1 + vk2 * vk2 + vk3 * vk3;
        }
        *(ushort4*)(qrawh + (size_t)(b * C16 + c16) * NN + nst) = sq4;
        *(ushort4*)(krawh + (size_t)(b * C16 + c16) * NN + nst) = sk4;
        ssq += __shfl_xor(ssq, 16, 64);
        ssq += __shfl_xor(ssq, 32, 64);
        ssk += __shfl_xor(ssk, 16, 64);
        ssk += __shfl_xor(ssk, 32, 64);
        if (lane < 16) {
            atomicAdd(nu2 + b * C16 + lane, ssq);
            atomicAdd(nu2 + 64 + b * C16 + lane, ssk);
        }
    }
}

// ========== K3: FRN + Mish (bf16 input), write bf16 Q/K in frag-major layout ==========
// q additionally scaled by log2(e) so attention can use exp2.
__global__ __launch_bounds__(256) void frn_mish_kernel(
        const unsigned short* __restrict__ qrawh, const unsigned short* __restrict__ krawh,
        const float* __restrict__ nu2, const float* __restrict__ eps_q,
        const float* __restrict__ eps_k, unsigned short* __restrict__ qb,
        unsigned short* __restrict__ kb) {
    int blk = blockIdx.x;
    int tensor = blk >> 6;
    int b = (blk >> 4) & 3;
    int ch = blk & 15;
    const unsigned short* raw = tensor ? krawh : qrawh;
    const float* eps = tensor ? eps_k : eps_q;
    unsigned short* outp = tensor ? kb : qb;
    const float* nu = nu2 + tensor * 64 + b * C16;
    float scale = tensor ? 1.0f : 1.44269504f;
    int n = ch * 256 + threadIdx.x;
    union { unsigned short s[16]; uint4 u[2]; } pk;
    for (int o = 0; o < C16; ++o) {
        float r = bf2f(raw[(size_t)(b * C16 + o) * NN + n]);
        float v = r * rsqrtf(nu[o] * (1.f / (float)NN) + fabsf(eps[o]));
        float sp = fmaxf(v, 0.f) + log1pf(expf(-fabsf(v)));   // stable softplus
        pk.s[o] = f2bf(v * tanhf(sp) * scale);
    }
    size_t base = ((size_t)b * 128 + (n >> 5)) * 512 + (size_t)(n & 31) * 8;
    *(uint4*)(outp + base)       = pk.u[0];   // o = 0..7  (lh=0)
    *(uint4*)(outp + base + 256) = pk.u[1];   // o = 8..15 (lh=1)
}

// exp2 + pack to bf16 A-frags (half-lane exchange); lsum accumulated
__device__ __forceinline__ void pack_p(
        floatx16 sc, float mneg, bool hi, short8* A0, short8* A1, float* lsum) {
    unsigned pk[8];
    float ls = 0.f;
#pragma unroll
    for (int p = 0; p < 8; ++p) {
        float e0 = EXP2(sc[2 * p] + mneg);
        float e1 = EXP2(sc[2 * p + 1] + mneg);
        ls += e0 + e1;
        pk[p] = __builtin_amdgcn_perm(__float_as_uint(e1), __float_as_uint(e0), 0x07060302u);
    }
    *lsum += ls;
    unsigned xk[8];
#pragma unroll
    for (int p = 0; p < 8; ++p) xk[p] = (unsigned)__shfl_xor((int)pk[p], 32, 64);
    union { unsigned u[4]; short8 s; } a0, a1;
    a0.u[0] = hi ? xk[2] : pk[0]; a0.u[1] = hi ? xk[3] : pk[1];
    a0.u[2] = hi ? pk[2] : xk[0]; a0.u[3] = hi ? pk[3] : xk[1];
    a1.u[0] = hi ? xk[6] : pk[4]; a1.u[1] = hi ? xk[7] : pk[5];
    a1.u[2] = hi ? pk[6] : xk[4]; a1.u[3] = hi ? pk[7] : xk[5];
    *A0 = a0.s; *A1 = a1.s;
}

// ========== K4: attention, j=64 c=128 per block, all loads frag-coalesced ==========
// grid 512: cs = id&1 (128-c), b = (id>>1)&3, jt = id>>3. 2 blocks/CU.
// Wave w streams k in [1024w, 1024w+1024) in 32-k steps.
__global__ __launch_bounds__(256, 2) void attn_kernel(
        const unsigned short* __restrict__ qb, const unsigned short* __restrict__ kb,
        const unsigned short* __restrict__ vb, const float* __restrict__ x,
        const float* __restrict__ gamma_p, float* __restrict__ out) {
    __shared__ float mp[4][2][32];
    __shared__ float lpart[4][2][32];
    __shared__ float obuf[4][32][33];

    int tid = threadIdx.x;
    int wv_ = __builtin_amdgcn_readfirstlane(tid >> 6);
    int lane = tid & 63;
    int l31 = lane & 31, lh = lane >> 5;
    bool hi = (lh != 0);
    int id = blockIdx.x;
    int cs = id & 1, b = (id >> 1) & 3, jt = id >> 3;
    int jbase = jt * 64, cb = cs * 128;
    int lane8 = lane * 8;

    const unsigned short* qfb = qb + ((size_t)b * 128 + (jbase >> 5)) * 512 + lane8;
    const unsigned short* kfb = kb + ((size_t)b * 128 + (wv_ * 32)) * 512 + lane8;

    short8 qf0 = *(const short8*)qfb;
    short8 qf1 = *(const short8*)(qfb + 512);

    floatx16 z16 = {0,0,0,0,0,0,0,0,0,0,0,0,0,0,0,0};

    // ---- pre-pass: true row max over this wave's k-range, 4-frag lookahead ----
    float mx0 = -INFINITY, mx1 = -INFINITY;
    {
        short8 ka[4];
#pragma unroll
        for (int t = 0; t < 4; ++t)
            ka[t] = *(const short8*)(kfb + (size_t)t * 512);
#pragma unroll 4
        for (int s = 0; s < 32; ++s) {
            short8 a = ka[s & 3];
            floatx16 s0 = __builtin_amdgcn_mfma_f32_32x32x16_bf16(a, qf0, z16, 0, 0, 0);
            floatx16 s1 = __builtin_amdgcn_mfma_f32_32x32x16_bf16(a, qf1, z16, 0, 0, 0);
            ka[s & 3] = *(const short8*)(kfb + (size_t)((s + 4) & 31) * 512);
#pragma unroll
            for (int r = 0; r < 16; ++r) {
                mx0 = fmaxf(mx0, s0[r]);
                mx1 = fmaxf(mx1, s1[r]);
            }
        }
    }
    mx0 = fmaxf(mx0, __shfl_xor(mx0, 32, 64));
    mx1 = fmaxf(mx1, __shfl_xor(mx1, 32, 64));
    if (lh == 0) { mp[wv_][0][l31] = mx0; mp[wv_][1][l31] = mx1; }
    __syncthreads();
    float mneg0 = -fmaxf(fmaxf(mp[0][0][l31], mp[1][0][l31]),
                         fmaxf(mp[2][0][l31], mp[3][0][l31]));
    float mneg1 = -fmaxf(fmaxf(mp[0][1][l31], mp[1][1][l31]),
                         fmaxf(mp[2][1][l31], mp[3][1][l31]));

    // ---- main loop ----
    floatx16 acc0[4], acc1[4];
#pragma unroll
    for (int cg = 0; cg < 4; ++cg) { acc0[cg] = z16; acc1[cg] = z16; }
    float lsum0 = 0.f, lsum1 = 0.f;

    const unsigned short* vp0 = vb + (((size_t)b * 8 + cs * 4 + 0) * 256 + wv_ * 64) * 512 + lane8;
    const unsigned short* vp1 = vb + (((size_t)b * 8 + cs * 4 + 1) * 256 + wv_ * 64) * 512 + lane8;
    const unsigned short* vp2 = vb + (((size_t)b * 8 + cs * 4 + 2) * 256 + wv_ * 64) * 512 + lane8;
    const unsigned short* vp3 = vb + (((size_t)b * 8 + cs * 4 + 3) * 256 + wv_ * 64) * 512 + lane8;

    short8 ak = *(const short8*)kfb;
#pragma unroll 1
    for (int step = 0; step < 32; ++step) {
        short8 vf0a = *(const short8*)vp0, vf0b = *(const short8*)(vp0 + 512);
        short8 vf1a = *(const short8*)vp1, vf1b = *(const short8*)(vp1 + 512);
        short8 vf2a = *(const short8*)vp2, vf2b = *(const short8*)(vp2 + 512);
        short8 vf3a = *(const short8*)vp3, vf3b = *(const short8*)(vp3 + 512);
        floatx16 sc0 = __builtin_amdgcn_mfma_f32_32x32x16_bf16(ak, qf0, z16, 0, 0, 0);
        floatx16 sc1 = __builtin_amdgcn_mfma_f32_32x32x16_bf16(ak, qf1, z16, 0, 0, 0);
        ak = *(const short8*)(kfb + (size_t)((step + 1) & 31) * 512);
        short8 A00, A01, A10, A11;
        pack_p(sc0, mneg0, hi, &A00, &A01, &lsum0);
        pack_p(sc1, mneg1, hi, &A10, &A11, &lsum1);
        acc0[0] = __builtin_amdgcn_mfma_f32_32x32x16_bf16(A00, vf0a, acc0[0], 0, 0, 0);
        acc0[0] = __builtin_amdgcn_mfma_f32_32x32x16_bf16(A01, vf0b, acc0[0], 0, 0, 0);
        acc1[0] = __builtin_amdgcn_mfma_f32_32x32x16_bf16(A10, vf0a, acc1[0], 0, 0, 0);
        acc1[0] = __builtin_amdgcn_mfma_f32_32x32x16_bf16(A11, vf0b, acc1[0], 0, 0, 0);
        acc0[1] = __builtin_amdgcn_mfma_f32_32x32x16_bf16(A00, vf1a, acc0[1], 0, 0, 0);
        acc0[1] = __builtin_amdgcn_mfma_f32_32x32x16_bf16(A01, vf1b, acc0[1], 0, 0, 0);
        acc1[1] = __builtin_amdgcn_mfma_f32_32x32x16_bf16(A10, vf1a, acc1[1], 0, 0, 0);
        acc1[1] = __builtin_amdgcn_mfma_f32_32x32x16_bf16(A11, vf1b, acc1[1], 0, 0, 0);
        acc0[2] = __builtin_amdgcn_mfma_f32_32x32x16_bf16(A00, vf2a, acc0[2], 0, 0, 0);
        acc0[2] = __builtin_amdgcn_mfma_f32_32x32x16_bf16(A01, vf2b, acc0[2], 0, 0, 0);
        acc1[2] = __builtin_amdgcn_mfma_f32_32x32x16_bf16(A10, vf2a, acc1[2], 0, 0, 0);
        acc1[2] = __builtin_amdgcn_mfma_f32_32x32x16_bf16(A11, vf2b, acc1[2], 0, 0, 0);
        acc0[3] = __builtin_amdgcn_mfma_f32_32x32x16_bf16(A00, vf3a, acc0[3], 0, 0, 0);
        acc0[3] = __builtin_amdgcn_mfma_f32_32x32x16_bf16(A01, vf3b, acc0[3], 0, 0, 0);
        acc1[3] = __builtin_amdgcn_mfma_f32_32x32x16_bf16(A10, vf3a, acc1[3], 0, 0, 0);
        acc1[3] = __builtin_amdgcn_mfma_f32_32x32x16_bf16(A11, vf3b, acc1[3], 0, 0, 0);
        vp0 += 1024; vp1 += 1024; vp2 += 1024; vp3 += 1024;
    }

    lsum0 += __shfl_xor(lsum0, 32, 64);
    lsum1 += __shfl_xor(lsum1, 32, 64);
    if (lh == 0) { lpart[wv_][0][l31] = lsum0; lpart[wv_][1][l31] = lsum1; }
    __syncthreads();

    int j31 = tid & 31;
    float gamma = gamma_p[0];
    float gl0 = gamma / (lpart[0][0][j31] + lpart[1][0][j31] + lpart[2][0][j31] + lpart[3][0][j31]);
    float gl1 = gamma / (lpart[0][1][j31] + lpart[1][1][j31] + lpart[2][1][j31] + lpart[3][1][j31]);
    const float* xbb = x + (size_t)b * CC * NN;
    float* obb = out + (size_t)b * CC * NN;
    int hofs = lh * 4;
    int cgrp = tid >> 5;
#pragma unroll
    for (int jg = 0; jg < 2; ++jg) {
        float gl = jg ? gl1 : gl0;
#pragma unroll
        for (int cg = 0; cg < 4; ++cg) {
            __syncthreads();
            const floatx16& a = jg ? acc1[cg] : acc0[cg];
#pragma unroll
            for (int r = 0; r < 16; ++r) {
                int row = (r & 3) + 8 * (r >> 2) + hofs;
                obuf[wv_][row][l31] = a[r];
            }
            __syncthreads();
#pragma unroll
            for (int i = 0; i < 4; ++i) {
                int c = cgrp * 4 + i;
                float val = obuf[0][j31][c] + obuf[1][j31][c] + obuf[2][j31][c] + obuf[3][j31][c];
                size_t oidx = (size_t)(cb + cg * 32 + c) * NN + jbase + jg * 32 + j31;
                obb[oidx] = fmaf(gl, val, xbb[oidx]);
            }
        }
    }
}

extern "C" void kernel_launch(void* const* d_in, const int* in_sizes, int n_in,
                              void* d_out, int out_size, void* d_ws, size_t ws_size,
                              hipStream_t stream) {
    const float* x     = (const float*)d_in[0];
    const float* wq    = (const float*)d_in[1];
    const float* bq    = (const float*)d_in[2];
    const float* wk    = (const float*)d_in[3];
    const float* bk    = (const float*)d_in[4];
    const float* wv    = (const float*)d_in[5];
    const float* bv    = (const float*)d_in[6];
    const float* gamma = (const float*)d_in[7];
    const float* eps_q = (const float*)d_in[8];
    const float* eps_k = (const float*)d_in[9];
    float* out = (float*)d_out;

    char* ws = (char*)d_ws;
    unsigned short* qrawh = (unsigned short*)ws;                     // 512 KB (1 MB slot)
    unsigned short* krawh = (unsigned short*)(ws + (1u << 20));      // 512 KB (1 MB slot)
    float* nu2  = (float*)(ws + (2u << 20));                         // 512 B
    unsigned short* qb = (unsigned short*)(ws + (2u << 20) + 4096);  // 512 KB
    unsigned short* kb = qb + (size_t)NB * NN * C16;                 // 512 KB
    unsigned short* vb = kb + (size_t)NB * NN * C16;                 // 8 MB
    unsigned short* xT = vb + (size_t)NB * CC * NN;                  // 8 MB
    unsigned short* wvb = xT + (size_t)NB * NN * CC;                 // 128 KB
    unsigned short* wqkb = wvb + (size_t)CC * CC;                    // 48 KB

    prep_kernel<<<dim3(1112), dim3(256), 0, stream>>>(x, wv, wq, wk, xT, wvb, wqkb, nu2);
    conv_kernel<<<dim3(768), dim3(256), 0, stream>>>(xT, wvb, wqkb, bv, bq, bk, vb, qrawh, krawh, nu2);
    frn_mish_kernel<<<dim3(128), dim3(256), 0, stream>>>(qrawh, krawh, nu2, eps_q, eps_k, qb, kb);
    attn_kernel<<<dim3(512), dim3(256), 0, stream>>>(qb, kb, vb, x, gamma, out);
}

// Round 12
// 165.477 us; speedup vs baseline: 1.6093x; 1.1089x over previous
//
#include <hip/hip_runtime.h>
#include <stdint.h>

#define NB 4
#define CC 256
#define C16 16
#define HH 64
#define WW 64
#define NN 4096

typedef __attribute__((ext_vector_type(8))) short short8;
typedef __attribute__((ext_vector_type(4))) float floatx4;
typedef __attribute__((ext_vector_type(16))) float floatx16;

#if __has_builtin(__builtin_amdgcn_exp2f)
#define EXP2(x) __builtin_amdgcn_exp2f(x)
#else
#define EXP2(x) exp2f(x)
#endif

__device__ __forceinline__ unsigned short f2bf(float f) {
    union { float f; unsigned u; } v; v.f = f;
    unsigned r = v.u + 0x7fffu + ((v.u >> 16) & 1u);
    return (unsigned short)(r >> 16);
}
__device__ __forceinline__ float bf2f(unsigned short h) {
    union { unsigned u; float f; } v; v.u = (unsigned)h << 16;
    return v.f;
}

// Fragment-major layouts (frag = 32 rows x 16 k = 64 lanes x 8 bf16 = 1KB):
//   qb/kb: frag f = b*128 + (n>>5); addr = f*512 + (n&31 + 32*(o>>3))*8 + (o&7)
//   vb:    frag f = (b*8 + (c>>5))*256 + (n>>4); addr = f*512 + (c&31 + 32*((n>>3)&1))*8 + (n&7)

// ========== K1: cast x->xT bf16 [b][n][c] (vectorized); cast wv/wq/wk; zero nu2 ==========
__global__ __launch_bounds__(256) void prep_kernel(
        const float* __restrict__ x, const float* __restrict__ wv,
        const float* __restrict__ wq, const float* __restrict__ wk,
        unsigned short* __restrict__ xT, unsigned short* __restrict__ wvb,
        unsigned short* __restrict__ wqkb, float* __restrict__ nu2) {
    int bid = blockIdx.x;
    if (bid < 1024) {
        __shared__ float tile_t[64][65];   // [n-local][c-local], pad 65: 2-way free
        int nt = bid & 63, ct = (bid >> 6) & 3, b = bid >> 8;
        int n0 = nt * 64, c0 = ct * 64;
        int tid = threadIdx.x;
        int rg = tid >> 4, f = tid & 15;
        const float* xb = x + ((size_t)b * CC + c0) * NN + n0;
#pragma unroll
        for (int p = 0; p < 4; ++p) {
            int c = p * 16 + rg;
            float4 v = *(const float4*)(xb + (size_t)c * NN + f * 4);
            tile_t[f * 4 + 0][c] = v.x;
            tile_t[f * 4 + 1][c] = v.y;
            tile_t[f * 4 + 2][c] = v.z;
            tile_t[f * 4 + 3][c] = v.w;
        }
        __syncthreads();
        unsigned short* xtb = xT + ((size_t)b * NN + n0) * CC + c0;
#pragma unroll
        for (int p = 0; p < 4; ++p) {
            int n = p * 16 + rg;
            ushort4 st;
            st.x = f2bf(tile_t[n][f * 4 + 0]);
            st.y = f2bf(tile_t[n][f * 4 + 1]);
            st.z = f2bf(tile_t[n][f * 4 + 2]);
            st.w = f2bf(tile_t[n][f * 4 + 3]);
            *(ushort4*)(xtb + (size_t)n * CC + f * 4) = st;
        }
    } else {
        int idx = (bid - 1024) * 256 + threadIdx.x;
        if (bid == 1024 && threadIdx.x < 128) nu2[threadIdx.x] = 0.f;
        if (idx < 16384) {
            float4 v = *(const float4*)(wv + idx * 4);
            ushort4 o;
            o.x = f2bf(v.x); o.y = f2bf(v.y); o.z = f2bf(v.z); o.w = f2bf(v.w);
            *(ushort4*)(wvb + idx * 4) = o;
        } else if (idx < 16384 + 6144) {
            int base = (idx - 16384) * 4;
#pragma unroll
            for (int u = 0; u < 4; ++u) {
                int e = base + u;
                int t = e / 12288;
                int i = e - t * 12288;
                int tap = i >> 12, o = (i >> 8) & 15, c = i & 255;
                const float* src = t ? wk : wq;
                wqkb[e] = f2bf(src[o * 768 + c * 3 + tap]);
            }
        }
    }
}

// ========== K2: conv_v (0..511) + conv_qk w/ FRN-ssq atomics (512..767) ==========
__global__ __launch_bounds__(256) void conv_kernel(
        const unsigned short* __restrict__ xT, const unsigned short* __restrict__ wvb,
        const unsigned short* __restrict__ wqkb, const float* __restrict__ bv,
        const float* __restrict__ bq, const float* __restrict__ bk,
        unsigned short* __restrict__ vb, unsigned short* __restrict__ qrawh,
        unsigned short* __restrict__ krawh, float* __restrict__ nu2) {
    int bid = blockIdx.x;
    int tid = threadIdx.x;
    int wv_ = tid >> 6, lane = tid & 63;
    int q16 = lane >> 4, c16 = lane & 15;
    if (bid < 512) {
        int ntile = bid & 63, b = (bid >> 6) & 3, ch = bid >> 8;
        int n0 = ntile * 64;
        int cb = ch * 128 + wv_ * 32;
        floatx4 fzero = {0.f, 0.f, 0.f, 0.f};
        floatx4 acc[2][4];
        for (int ct = 0; ct < 2; ++ct)
            for (int nt = 0; nt < 4; ++nt) acc[ct][nt] = fzero;
        const unsigned short* xb = xT + ((size_t)b * NN + n0) * CC;
        for (int kc = 0; kc < 8; ++kc) {
            int ko = kc * 32 + q16 * 8;
            short8 a0 = *(const short8*)(wvb + (size_t)(cb + c16) * CC + ko);
            short8 a1 = *(const short8*)(wvb + (size_t)(cb + 16 + c16) * CC + ko);
            short8 bf[4];
#pragma unroll
            for (int nt = 0; nt < 4; ++nt)
                bf[nt] = *(const short8*)(xb + (size_t)(nt * 16 + c16) * CC + ko);
#pragma unroll
            for (int nt = 0; nt < 4; ++nt) {
                acc[0][nt] = __builtin_amdgcn_mfma_f32_16x16x32_bf16(bf[nt], a0, acc[0][nt], 0, 0, 0);
                acc[1][nt] = __builtin_amdgcn_mfma_f32_16x16x32_bf16(bf[nt], a1, acc[1][nt], 0, 0, 0);
            }
        }
        // C: row = q16*4+r -> n-local, col = c16 -> c-local. ushort4 frag-major stores.
        float bv0 = bv[cb + c16], bv1 = bv[cb + 16 + c16];
        int off = 32 * 8 * (q16 >> 1) + (q16 & 1) * 4 + c16 * 8;
#pragma unroll
        for (int ct = 0; ct < 2; ++ct) {
            float bvv = ct ? bv1 : bv0;
#pragma unroll
            for (int nt = 0; nt < 4; ++nt) {
                size_t fb = (((size_t)b * 8 + ch * 4 + wv_) * 256 + (n0 >> 4) + nt) * 512;
                ushort4 st;
                st.x = f2bf(acc[ct][nt][0] + bvv);
                st.y = f2bf(acc[ct][nt][1] + bvv);
                st.z = f2bf(acc[ct][nt][2] + bvv);
                st.w = f2bf(acc[ct][nt][3] + bvv);
                *(ushort4*)(vb + fb + off + ct * 16 * 8) = st;
            }
        }
    } else {
        int cv = bid - 512;
        int nb2 = cv & 63, b = cv >> 6;
        int nl = nb2 * 64 + wv_ * 16 + c16;     // load-n (A-frag m index)
        int h = nl >> 6, w = nl & 63;
        bool vm1 = (w != 0), vp1 = (w != 63);
        bool vm64 = (h != 0), vp64 = (h != 63);
        short8 zero8 = {0, 0, 0, 0, 0, 0, 0, 0};
        floatx4 accq = {0.f, 0.f, 0.f, 0.f}, acck = {0.f, 0.f, 0.f, 0.f};
        const unsigned short* xb = xT + (size_t)b * NN * CC;
        const unsigned short* wrow = wqkb + c16 * 256;
        for (int kc = 0; kc < 8; ++kc) {
            int ko = kc * 32 + q16 * 8;
            short8 b0 = *(const short8*)(xb + (size_t)nl * CC + ko);
            short8 bm1 = vm1 ? *(const short8*)(xb + (size_t)(nl - 1) * CC + ko) : zero8;
            short8 bp1 = vp1 ? *(const short8*)(xb + (size_t)(nl + 1) * CC + ko) : zero8;
            short8 bm64 = vm64 ? *(const short8*)(xb + (size_t)(nl - 64) * CC + ko) : zero8;
            short8 bp64 = vp64 ? *(const short8*)(xb + (size_t)(nl + 64) * CC + ko) : zero8;
            short8 aq0 = *(const short8*)(wrow + 0 * 4096 + ko);
            short8 aq1 = *(const short8*)(wrow + 1 * 4096 + ko);
            short8 aq2 = *(const short8*)(wrow + 2 * 4096 + ko);
            short8 ak0 = *(const short8*)(wrow + 12288 + 0 * 4096 + ko);
            short8 ak1 = *(const short8*)(wrow + 12288 + 1 * 4096 + ko);
            short8 ak2 = *(const short8*)(wrow + 12288 + 2 * 4096 + ko);
            accq = __builtin_amdgcn_mfma_f32_16x16x32_bf16(bm1, aq0, accq, 0, 0, 0);
            accq = __builtin_amdgcn_mfma_f32_16x16x32_bf16(b0, aq1, accq, 0, 0, 0);
            accq = __builtin_amdgcn_mfma_f32_16x16x32_bf16(bp1, aq2, accq, 0, 0, 0);
            acck = __builtin_amdgcn_mfma_f32_16x16x32_bf16(bm64, ak0, acck, 0, 0, 0);
            acck = __builtin_amdgcn_mfma_f32_16x16x32_bf16(b0, ak1, acck, 0, 0, 0);
            acck = __builtin_amdgcn_mfma_f32_16x16x32_bf16(bp64, ak2, acck, 0, 0, 0);
        }
        // C: row = q16*4+r -> n, col = c16 -> o. bf16 ushort4 stores.
        int nst = nb2 * 64 + wv_ * 16 + q16 * 4;
        float bqv = bq[c16], bkv = bk[c16];
        ushort4 sq4, sk4;
        float ssq = 0.f, ssk = 0.f;
        {
            float vq0 = accq[0] + bqv, vq1 = accq[1] + bqv, vq2 = accq[2] + bqv, vq3 = accq[3] + bqv;
            float vk0 = acck[0] + bkv, vk1 = acck[1] + bkv, vk2 = acck[2] + bkv, vk3 = acck[3] + bkv;
            sq4.x = f2bf(vq0); sq4.y = f2bf(vq1); sq4.z = f2bf(vq2); sq4.w = f2bf(vq3);
            sk4.x = f2bf(vk0); sk4.y = f2bf(vk1); sk4.z = f2bf(vk2); sk4.w = f2bf(vk3);
            ssq = vq0 * vq0 + vq1 * vq1 + vq2 * vq2 + vq3 * vq3;
            ssk = vk0 * vk0 + vk1 * vk1 + vk2 * vk2 + vk3 * vk3;
        }
        *(ushort4*)(qrawh + (size_t)(b * C16 + c16) * NN + nst) = sq4;
        *(ushort4*)(krawh + (size_t)(b * C16 + c16) * NN + nst) = sk4;
        ssq += __shfl_xor(ssq, 16, 64);
        ssq += __shfl_xor(ssq, 32, 64);
        ssk += __shfl_xor(ssk, 16, 64);
        ssk += __shfl_xor(ssk, 32, 64);
        if (lane < 16) {
            atomicAdd(nu2 + b * C16 + lane, ssq);
            atomicAdd(nu2 + 64 + b * C16 + lane, ssk);
        }
    }
}

// ========== K3: FRN + Mish (bf16 input), frag-major out; 512 blocks, 4 ch/thread ==========
// q additionally scaled by log2(e) so attention can use exp2.
__global__ __launch_bounds__(256) void frn_mish_kernel(
        const unsigned short* __restrict__ qrawh, const unsigned short* __restrict__ krawh,
        const float* __restrict__ nu2, const float* __restrict__ eps_q,
        const float* __restrict__ eps_k, unsigned short* __restrict__ qb,
        unsigned short* __restrict__ kb) {
    int blk = blockIdx.x;                 // 512 = tensor(2) x b(4) x nchunk(64)
    int tensor = blk >> 8;
    int b = (blk >> 6) & 3;
    int nch = blk & 63;
    const unsigned short* raw = tensor ? krawh : qrawh;
    const float* eps = tensor ? eps_k : eps_q;
    unsigned short* outp = tensor ? kb : qb;
    const float* nu = nu2 + tensor * 64 + b * C16;
    float scale = tensor ? 1.0f : 1.44269504f;
    int n = nch * 64 + (threadIdx.x & 63);
    int oq = threadIdx.x >> 6;            // 0..3 -> channels oq*4..oq*4+3
    ushort4 pk4;
#pragma unroll
    for (int i = 0; i < 4; ++i) {
        int o = oq * 4 + i;
        float r = bf2f(raw[(size_t)(b * C16 + o) * NN + n]);
        float v = r * rsqrtf(nu[o] * (1.f / (float)NN) + fabsf(eps[o]));
        float sp = fmaxf(v, 0.f) + log1pf(expf(-fabsf(v)));   // stable softplus
        float m = v * tanhf(sp) * scale;
        ((unsigned short*)&pk4)[i] = f2bf(m);
    }
    size_t base = ((size_t)b * 128 + (n >> 5)) * 512 + (size_t)(n & 31) * 8
                + (size_t)(oq >> 1) * 256 + (oq & 1) * 4;
    *(ushort4*)(outp + base) = pk4;
}

// exp2 (NO shift — softmax is shift-invariant; S range fits f32/bf16 exponent span)
// + pack to bf16 A-frags (half-lane exchange); lsum accumulated in f32 pre-rounding.
__device__ __forceinline__ void pack_p0(
        floatx16 sc, bool hi, short8* A0, short8* A1, float* lsum) {
    unsigned pk[8];
    float ls = 0.f;
#pragma unroll
    for (int p = 0; p < 8; ++p) {
        float e0 = EXP2(sc[2 * p]);
        float e1 = EXP2(sc[2 * p + 1]);
        ls += e0 + e1;
        pk[p] = __builtin_amdgcn_perm(__float_as_uint(e1), __float_as_uint(e0), 0x07060302u);
    }
    *lsum += ls;
    unsigned xk[8];
#pragma unroll
    for (int p = 0; p < 8; ++p) xk[p] = (unsigned)__shfl_xor((int)pk[p], 32, 64);
    union { unsigned u[4]; short8 s; } a0, a1;
    a0.u[0] = hi ? xk[2] : pk[0]; a0.u[1] = hi ? xk[3] : pk[1];
    a0.u[2] = hi ? pk[2] : xk[0]; a0.u[3] = hi ? pk[3] : xk[1];
    a1.u[0] = hi ? xk[6] : pk[4]; a1.u[1] = hi ? xk[7] : pk[5];
    a1.u[2] = hi ? pk[6] : xk[4]; a1.u[3] = hi ? pk[7] : xk[5];
    *A0 = a0.s; *A1 = a1.s;
}

// ========== K4: attention, j=64 c=128 per block, NO max pre-pass ==========
// grid 512: cs = id&1 (128-c), b = (id>>1)&3, jt = id>>3. 2 blocks/CU.
// Wave w streams k in [1024w, 1024w+1024) in 32-k steps.
__global__ __launch_bounds__(256, 2) void attn_kernel(
        const unsigned short* __restrict__ qb, const unsigned short* __restrict__ kb,
        const unsigned short* __restrict__ vb, const float* __restrict__ x,
        const float* __restrict__ gamma_p, float* __restrict__ out) {
    __shared__ float lpart[4][2][32];
    __shared__ float obuf[4][32][33];

    int tid = threadIdx.x;
    int wv_ = __builtin_amdgcn_readfirstlane(tid >> 6);
    int lane = tid & 63;
    int l31 = lane & 31, lh = lane >> 5;
    bool hi = (lh != 0);
    int id = blockIdx.x;
    int cs = id & 1, b = (id >> 1) & 3, jt = id >> 3;
    int jbase = jt * 64, cb = cs * 128;
    int lane8 = lane * 8;

    const unsigned short* qfb = qb + ((size_t)b * 128 + (jbase >> 5)) * 512 + lane8;
    const unsigned short* kfb = kb + ((size_t)b * 128 + (wv_ * 32)) * 512 + lane8;

    short8 qf0 = *(const short8*)qfb;
    short8 qf1 = *(const short8*)(qfb + 512);

    floatx16 z16 = {0,0,0,0,0,0,0,0,0,0,0,0,0,0,0,0};
    floatx16 acc0[4], acc1[4];
#pragma unroll
    for (int cg = 0; cg < 4; ++cg) { acc0[cg] = z16; acc1[cg] = z16; }
    float lsum0 = 0.f, lsum1 = 0.f;

    const unsigned short* vp0 = vb + (((size_t)b * 8 + cs * 4 + 0) * 256 + wv_ * 64) * 512 + lane8;
    const unsigned short* vp1 = vb + (((size_t)b * 8 + cs * 4 + 1) * 256 + wv_ * 64) * 512 + lane8;
    const unsigned short* vp2 = vb + (((size_t)b * 8 + cs * 4 + 2) * 256 + wv_ * 64) * 512 + lane8;
    const unsigned short* vp3 = vb + (((size_t)b * 8 + cs * 4 + 3) * 256 + wv_ * 64) * 512 + lane8;

    short8 ak = *(const short8*)kfb;
#pragma unroll 1
    for (int step = 0; step < 32; ++step) {
        short8 vf0a = *(const short8*)vp0, vf0b = *(const short8*)(vp0 + 512);
        short8 vf1a = *(const short8*)vp1, vf1b = *(const short8*)(vp1 + 512);
        short8 vf2a = *(const short8*)vp2, vf2b = *(const short8*)(vp2 + 512);
        short8 vf3a = *(const short8*)vp3, vf3b = *(const short8*)(vp3 + 512);
        floatx16 sc0 = __builtin_amdgcn_mfma_f32_32x32x16_bf16(ak, qf0, z16, 0, 0, 0);
        floatx16 sc1 = __builtin_amdgcn_mfma_f32_32x32x16_bf16(ak, qf1, z16, 0, 0, 0);
        ak = *(const short8*)(kfb + (size_t)((step + 1) & 31) * 512);
        short8 A00, A01, A10, A11;
        pack_p0(sc0, hi, &A00, &A01, &lsum0);
        pack_p0(sc1, hi, &A10, &A11, &lsum1);
        acc0[0] = __builtin_amdgcn_mfma_f32_32x32x16_bf16(A00, vf0a, acc0[0], 0, 0, 0);
        acc0[0] = __builtin_amdgcn_mfma_f32_32x32x16_bf16(A01, vf0b, acc0[0], 0, 0, 0);
        acc1[0] = __builtin_amdgcn_mfma_f32_32x32x16_bf16(A10, vf0a, acc1[0], 0, 0, 0);
        acc1[0] = __builtin_amdgcn_mfma_f32_32x32x16_bf16(A11, vf0b, acc1[0], 0, 0, 0);
        acc0[1] = __builtin_amdgcn_mfma_f32_32x32x16_bf16(A00, vf1a, acc0[1], 0, 0, 0);
        acc0[1] = __builtin_amdgcn_mfma_f32_32x32x16_bf16(A01, vf1b, acc0[1], 0, 0, 0);
        acc1[1] = __builtin_amdgcn_mfma_f32_32x32x16_bf16(A10, vf1a, acc1[1], 0, 0, 0);
        acc1[1] = __builtin_amdgcn_mfma_f32_32x32x16_bf16(A11, vf1b, acc1[1], 0, 0, 0);
        acc0[2] = __builtin_amdgcn_mfma_f32_32x32x16_bf16(A00, vf2a, acc0[2], 0, 0, 0);
        acc0[2] = __builtin_amdgcn_mfma_f32_32x32x16_bf16(A01, vf2b, acc0[2], 0, 0, 0);
        acc1[2] = __builtin_amdgcn_mfma_f32_32x32x16_bf16(A10, vf2a, acc1[2], 0, 0, 0);
        acc1[2] = __builtin_amdgcn_mfma_f32_32x32x16_bf16(A11, vf2b, acc1[2], 0, 0, 0);
        acc0[3] = __builtin_amdgcn_mfma_f32_32x32x16_bf16(A00, vf3a, acc0[3], 0, 0, 0);
        acc0[3] = __builtin_amdgcn_mfma_f32_32x32x16_bf16(A01, vf3b, acc0[3], 0, 0, 0);
        acc1[3] = __builtin_amdgcn_mfma_f32_32x32x16_bf16(A10, vf3a, acc1[3], 0, 0, 0);
        acc1[3] = __builtin_amdgcn_mfma_f32_32x32x16_bf16(A11, vf3b, acc1[3], 0, 0, 0);
        vp0 += 1024; vp1 += 1024; vp2 += 1024; vp3 += 1024;
    }

    lsum0 += __shfl_xor(lsum0, 32, 64);
    lsum1 += __shfl_xor(lsum1, 32, 64);
    if (lh == 0) { lpart[wv_][0][l31] = lsum0; lpart[wv_][1][l31] = lsum1; }
    __syncthreads();

    int j31 = tid & 31;
    float gamma = gamma_p[0];
    float gl0 = gamma / (lpart[0][0][j31] + lpart[1][0][j31] + lpart[2][0][j31] + lpart[3][0][j31]);
    float gl1 = gamma / (lpart[0][1][j31] + lpart[1][1][j31] + lpart[2][1][j31] + lpart[3][1][j31]);
    const float* xbb = x + (size_t)b * CC * NN;
    float* obb = out + (size_t)b * CC * NN;
    int hofs = lh * 4;
    int cgrp = tid >> 5;
#pragma unroll
    for (int jg = 0; jg < 2; ++jg) {
        float gl = jg ? gl1 : gl0;
#pragma unroll
        for (int cg = 0; cg < 4; ++cg) {
            __syncthreads();
            const floatx16& a = jg ? acc1[cg] : acc0[cg];
#pragma unroll
            for (int r = 0; r < 16; ++r) {
                int row = (r & 3) + 8 * (r >> 2) + hofs;
                obuf[wv_][row][l31] = a[r];
            }
            __syncthreads();
#pragma unroll
            for (int i = 0; i < 4; ++i) {
                int c = cgrp * 4 + i;
                float val = obuf[0][j31][c] + obuf[1][j31][c] + obuf[2][j31][c] + obuf[3][j31][c];
                size_t oidx = (size_t)(cb + cg * 32 + c) * NN + jbase + jg * 32 + j31;
                obb[oidx] = fmaf(gl, val, xbb[oidx]);
            }
        }
    }
}

extern "C" void kernel_launch(void* const* d_in, const int* in_sizes, int n_in,
                              void* d_out, int out_size, void* d_ws, size_t ws_size,
                              hipStream_t stream) {
    const float* x     = (const float*)d_in[0];
    const float* wq    = (const float*)d_in[1];
    const float* bq    = (const float*)d_in[2];
    const float* wk    = (const float*)d_in[3];
    const float* bk    = (const float*)d_in[4];
    const float* wv    = (const float*)d_in[5];
    const float* bv    = (const float*)d_in[6];
    const float* gamma = (const float*)d_in[7];
    const float* eps_q = (const float*)d_in[8];
    const float* eps_k = (const float*)d_in[9];
    float* out = (float*)d_out;

    char* ws = (char*)d_ws;
    unsigned short* qrawh = (unsigned short*)ws;                     // 512 KB (1 MB slot)
    unsigned short* krawh = (unsigned short*)(ws + (1u << 20));      // 512 KB (1 MB slot)
    float* nu2  = (float*)(ws + (2u << 20));                         // 512 B
    unsigned short* qb = (unsigned short*)(ws + (2u << 20) + 4096);  // 512 KB
    unsigned short* kb = qb + (size_t)NB * NN * C16;                 // 512 KB
    unsigned short* vb = kb + (size_t)NB * NN * C16;                 // 8 MB
    unsigned short* xT = vb + (size_t)NB * CC * NN;                  // 8 MB
    unsigned short* wvb = xT + (size_t)NB * NN * CC;                 // 128 KB
    unsigned short* wqkb = wvb + (size_t)CC * CC;                    // 48 KB

    prep_kernel<<<dim3(1112), dim3(256), 0, stream>>>(x, wv, wq, wk, xT, wvb, wqkb, nu2);
    conv_kernel<<<dim3(768), dim3(256), 0, stream>>>(xT, wvb, wqkb, bv, bq, bk, vb, qrawh, krawh, nu2);
    frn_mish_kernel<<<dim3(512), dim3(256), 0, stream>>>(qrawh, krawh, nu2, eps_q, eps_k, qb, kb);
    attn_kernel<<<dim3(512), dim3(256), 0, stream>>>(qb, kb, vb, x, gamma, out);
}